// Round 1
// baseline (668.477 us; speedup 1.0000x reference)
//
#include <hip/hip_runtime.h>
#include <math.h>

#define BN   4
#define CD   192
#define LSEQ 4096
#define DI   384
#define DTRK 12
#define DS   16
#define NJ   44

__device__ __forceinline__ float silu_f(float x) { return x / (1.f + __expf(-x)); }
__device__ __forceinline__ float softplus_f(float x) {
    return (x > 15.f) ? x : log1pf(__expf(x));
}

// ---------------------------------------------------------------------------
// K1: xz = in_proj(x).  x is (b, 192, L); out xp (b,384,L) and silu(z) (b,384,L)
// row-broadcast GEMM: out[e][l] = sum_c W[e][c] * x[c][l]
// grid (ltile=4, echunk=48, b=4), block 256, 4 l per thread, 16 e per block
// ---------------------------------------------------------------------------
__global__ __launch_bounds__(256) void k_inproj(const float* __restrict__ x,
                                                const float* __restrict__ w,
                                                float* __restrict__ xp,
                                                float* __restrict__ zs) {
    __shared__ float wt[16 * 192];
    const int b  = blockIdx.z;
    const int e0 = blockIdx.y * 16;
    const int l0 = blockIdx.x * 1024 + threadIdx.x * 4;
    for (int i = threadIdx.x; i < 16 * 192; i += 256) {
        int e = i / 192, c = i % 192;
        wt[i] = w[(size_t)(e0 + e) * 192 + c];
    }
    __syncthreads();
    float acc[16][4];
#pragma unroll
    for (int e = 0; e < 16; ++e) { acc[e][0] = acc[e][1] = acc[e][2] = acc[e][3] = 0.f; }
    const float* xb = x + (size_t)b * CD * LSEQ + l0;
    for (int c = 0; c < 192; c += 4) {
        float4 x0 = *(const float4*)(xb + (size_t)c * LSEQ);
        float4 x1 = *(const float4*)(xb + (size_t)(c + 1) * LSEQ);
        float4 x2 = *(const float4*)(xb + (size_t)(c + 2) * LSEQ);
        float4 x3 = *(const float4*)(xb + (size_t)(c + 3) * LSEQ);
#pragma unroll
        for (int e = 0; e < 16; ++e) {
            float4 wv = *(const float4*)&wt[e * 192 + c];
            acc[e][0] = fmaf(wv.x, x0.x, fmaf(wv.y, x1.x, fmaf(wv.z, x2.x, fmaf(wv.w, x3.x, acc[e][0]))));
            acc[e][1] = fmaf(wv.x, x0.y, fmaf(wv.y, x1.y, fmaf(wv.z, x2.y, fmaf(wv.w, x3.y, acc[e][1]))));
            acc[e][2] = fmaf(wv.x, x0.z, fmaf(wv.y, x1.z, fmaf(wv.z, x2.z, fmaf(wv.w, x3.z, acc[e][2]))));
            acc[e][3] = fmaf(wv.x, x0.w, fmaf(wv.y, x1.w, fmaf(wv.z, x2.w, fmaf(wv.w, x3.w, acc[e][3]))));
        }
    }
    const bool is_z = (e0 >= DI);
#pragma unroll
    for (int e = 0; e < 16; ++e) {
        float4 v = make_float4(acc[e][0], acc[e][1], acc[e][2], acc[e][3]);
        if (is_z) { v.x = silu_f(v.x); v.y = silu_f(v.y); v.z = silu_f(v.z); v.w = silu_f(v.w); }
        int row = is_z ? (e0 - DI + e) : (e0 + e);
        float* dst = (is_z ? zs : xp) + ((size_t)b * DI + row) * LSEQ + l0;
        *(float4*)dst = v;
    }
}

// ---------------------------------------------------------------------------
// K2: depthwise causal conv(4) + bias + silu.  (b,384,L) -> (b,384,L)
// ---------------------------------------------------------------------------
__global__ __launch_bounds__(256) void k_conv(const float* __restrict__ xp,
                                              const float* __restrict__ cw,
                                              const float* __restrict__ cb,
                                              float* __restrict__ xc) {
    const int d = blockIdx.y, b = blockIdx.z;
    const int l0 = blockIdx.x * 1024 + threadIdx.x * 4;
    const float w0 = cw[d * 4 + 0], w1 = cw[d * 4 + 1], w2 = cw[d * 4 + 2], w3 = cw[d * 4 + 3];
    const float bb = cb[d];
    const float* row = xp + ((size_t)b * DI + d) * LSEQ;
    float4 cur = *(const float4*)(row + l0);
    float4 pv;
    if (l0 == 0) pv = make_float4(0.f, 0.f, 0.f, 0.f);
    else         pv = *(const float4*)(row + l0 - 4);
    float o0 = fmaf(w0, pv.y, fmaf(w1, pv.z, fmaf(w2, pv.w, fmaf(w3, cur.x, bb))));
    float o1 = fmaf(w0, pv.z, fmaf(w1, pv.w, fmaf(w2, cur.x, fmaf(w3, cur.y, bb))));
    float o2 = fmaf(w0, pv.w, fmaf(w1, cur.x, fmaf(w2, cur.y, fmaf(w3, cur.z, bb))));
    float o3 = fmaf(w0, cur.x, fmaf(w1, cur.y, fmaf(w2, cur.z, fmaf(w3, cur.w, bb))));
    float4 o = make_float4(silu_f(o0), silu_f(o1), silu_f(o2), silu_f(o3));
    *(float4*)(xc + ((size_t)b * DI + d) * LSEQ + l0) = o;
}

// ---------------------------------------------------------------------------
// K3a: x_dbl partials. out[j][l] = sum_{d in part} xpw[j][d] * xc[d][l]
// grid (ltile=16, part=4, b=4), block 256 (1 l each), 96 d per part
// ---------------------------------------------------------------------------
__global__ __launch_bounds__(256) void k_xdbl(const float* __restrict__ xc,
                                              const float* __restrict__ xpw,
                                              float* __restrict__ xdp) {
    __shared__ float wt[NJ * 96];
    const int part = blockIdx.y, b = blockIdx.z;
    const int l = blockIdx.x * 256 + threadIdx.x;
    const int d0 = part * 96;
    for (int i = threadIdx.x; i < NJ * 96; i += 256) {
        int j = i / 96, dd = i % 96;
        wt[i] = xpw[(size_t)j * DI + d0 + dd];
    }
    __syncthreads();
    float acc[NJ];
#pragma unroll
    for (int j = 0; j < NJ; ++j) acc[j] = 0.f;
    const float* xcb = xc + ((size_t)b * DI + d0) * LSEQ + l;
    for (int dd = 0; dd < 96; dd += 4) {
        float v0 = xcb[(size_t)dd * LSEQ];
        float v1 = xcb[(size_t)(dd + 1) * LSEQ];
        float v2 = xcb[(size_t)(dd + 2) * LSEQ];
        float v3 = xcb[(size_t)(dd + 3) * LSEQ];
#pragma unroll
        for (int j = 0; j < NJ; ++j) {
            float4 wv = *(const float4*)&wt[j * 96 + dd];
            acc[j] = fmaf(wv.x, v0, fmaf(wv.y, v1, fmaf(wv.z, v2, fmaf(wv.w, v3, acc[j]))));
        }
    }
    float* dst = xdp + (size_t)(part * BN + b) * NJ * LSEQ + l;
#pragma unroll
    for (int j = 0; j < NJ; ++j) dst[(size_t)j * LSEQ] = acc[j];
}

// ---------------------------------------------------------------------------
// K3c: reduce 4 partials; route rows: j<12 -> dtr rows, 12..27 -> B, 28..43 -> C
// grid (ltile=16, j=44, b=4), block 256
// ---------------------------------------------------------------------------
__global__ __launch_bounds__(256) void k_xdbl_reduce(const float* __restrict__ xdp,
                                                     float* __restrict__ dtr,
                                                     float* __restrict__ Bm,
                                                     float* __restrict__ Cm) {
    const int j = blockIdx.y, b = blockIdx.z;
    const int l = blockIdx.x * 256 + threadIdx.x;
    float s = 0.f;
#pragma unroll
    for (int p = 0; p < 4; ++p)
        s += xdp[(size_t)(p * BN + b) * NJ * LSEQ + (size_t)j * LSEQ + l];
    if (j < DTRK)            dtr[((size_t)b * DTRK + j) * LSEQ + l] = s;
    else if (j < DTRK + DS)  Bm[((size_t)b * LSEQ + l) * DS + (j - DTRK)] = s;
    else                     Cm[((size_t)b * LSEQ + l) * DS + (j - DTRK - DS)] = s;
}

// ---------------------------------------------------------------------------
// K3b: dt = softplus(dt_r @ dtw^T + dtb). grid (ltile=16, echunk=24, b=4)
// ---------------------------------------------------------------------------
__global__ __launch_bounds__(256) void k_dt(const float* __restrict__ dtr,
                                            const float* __restrict__ dtw,
                                            const float* __restrict__ dtb,
                                            float* __restrict__ dt) {
    __shared__ float wt[16 * DTRK];
    __shared__ float bt[16];
    const int e0 = blockIdx.y * 16, b = blockIdx.z;
    const int l = blockIdx.x * 256 + threadIdx.x;
    if (threadIdx.x < 16 * DTRK)
        wt[threadIdx.x] = dtw[(size_t)(e0 + threadIdx.x / DTRK) * DTRK + threadIdx.x % DTRK];
    if (threadIdx.x < 16) bt[threadIdx.x] = dtb[e0 + threadIdx.x];
    __syncthreads();
    float acc[16];
#pragma unroll
    for (int e = 0; e < 16; ++e) acc[e] = 0.f;
    const float* rb = dtr + (size_t)b * DTRK * LSEQ + l;
#pragma unroll
    for (int r = 0; r < DTRK; ++r) {
        float v = rb[(size_t)r * LSEQ];
#pragma unroll
        for (int e = 0; e < 16; ++e) acc[e] = fmaf(wt[e * DTRK + r], v, acc[e]);
    }
    float* dst = dt + ((size_t)b * DI + e0) * LSEQ + l;
#pragma unroll
    for (int e = 0; e < 16; ++e) dst[(size_t)e * LSEQ] = softplus_f(acc[e] + bt[e]);
}

// ---------------------------------------------------------------------------
// K4: chunked selective scan + y + gate.  block = one (b,d), 64 threads = 64
// chunks of 64 steps. Phase1: local scans (h from 0) + decay products.
// Phase2: sequential carry scan over chunks in LDS. Phase3: replay with
// carry-in, y = sum_n h*C + D*xc, g = y * silu(z)  (zs holds silu(z)).
// ---------------------------------------------------------------------------
__global__ __launch_bounds__(64) void k_scan(const float* __restrict__ dt,
                                             const float* __restrict__ xc,
                                             const float* __restrict__ Bm,
                                             const float* __restrict__ Cm,
                                             const float* __restrict__ zs,
                                             const float* __restrict__ A_log,
                                             const float* __restrict__ Dp,
                                             float* __restrict__ g) {
    __shared__ float sP[64][DS];
    __shared__ float sH[64][DS];
    __shared__ float sC[64][DS];
    const int d = blockIdx.x, b = blockIdx.y;
    const int ch = threadIdx.x;
    float An[DS];
#pragma unroll
    for (int n = 0; n < DS; ++n) An[n] = -__expf(A_log[(size_t)d * DS + n]);
    const float Dd = Dp[d];
    const float* dtrow = dt + ((size_t)b * DI + d) * LSEQ;
    const float* xcrow = xc + ((size_t)b * DI + d) * LSEQ;
    const float* zrow  = zs + ((size_t)b * DI + d) * LSEQ;
    float* grow = g + ((size_t)b * DI + d) * LSEQ;
    const int l0 = ch * 64;

    float h[DS], p[DS];
#pragma unroll
    for (int n = 0; n < DS; ++n) { h[n] = 0.f; p[n] = 1.f; }
    for (int i = 0; i < 64; ++i) {
        const int l = l0 + i;
        const float dtv = dtrow[l];
        const float xcv = xcrow[l];
        const float dx = dtv * xcv;
        const float4* bp = (const float4*)(Bm + ((size_t)b * LSEQ + l) * DS);
        float4 B0 = bp[0], B1 = bp[1], B2 = bp[2], B3 = bp[3];
        float Bv[DS] = {B0.x, B0.y, B0.z, B0.w, B1.x, B1.y, B1.z, B1.w,
                        B2.x, B2.y, B2.z, B2.w, B3.x, B3.y, B3.z, B3.w};
#pragma unroll
        for (int n = 0; n < DS; ++n) {
            float dA = __expf(dtv * An[n]);
            p[n] *= dA;
            h[n] = fmaf(dA, h[n], dx * Bv[n]);
        }
    }
#pragma unroll
    for (int n = 0; n < DS; ++n) { sP[ch][n] = p[n]; sH[ch][n] = h[n]; }
    __syncthreads();
    if (ch < DS) {
        float hc = 0.f;
        for (int c = 0; c < 64; ++c) {
            sC[c][ch] = hc;
            hc = fmaf(sP[c][ch], hc, sH[c][ch]);
        }
    }
    __syncthreads();
#pragma unroll
    for (int n = 0; n < DS; ++n) h[n] = sC[ch][n];
    for (int i = 0; i < 64; ++i) {
        const int l = l0 + i;
        const float dtv = dtrow[l];
        const float xcv = xcrow[l];
        const float zv  = zrow[l];
        const float dx = dtv * xcv;
        const float4* bp = (const float4*)(Bm + ((size_t)b * LSEQ + l) * DS);
        const float4* cp = (const float4*)(Cm + ((size_t)b * LSEQ + l) * DS);
        float4 B0 = bp[0], B1 = bp[1], B2 = bp[2], B3 = bp[3];
        float4 C0 = cp[0], C1 = cp[1], C2 = cp[2], C3 = cp[3];
        float Bv[DS] = {B0.x, B0.y, B0.z, B0.w, B1.x, B1.y, B1.z, B1.w,
                        B2.x, B2.y, B2.z, B2.w, B3.x, B3.y, B3.z, B3.w};
        float Cv[DS] = {C0.x, C0.y, C0.z, C0.w, C1.x, C1.y, C1.z, C1.w,
                        C2.x, C2.y, C2.z, C2.w, C3.x, C3.y, C3.z, C3.w};
        float y = 0.f;
#pragma unroll
        for (int n = 0; n < DS; ++n) {
            float dA = __expf(dtv * An[n]);
            h[n] = fmaf(dA, h[n], dx * Bv[n]);
            y = fmaf(h[n], Cv[n], y);
        }
        grow[l] = (y + Dd * xcv) * zv;
    }
}

// ---------------------------------------------------------------------------
// K5: out[c][l] = sum_d wout[c][d] * g[d][l].  grid (ltile=4, cchunk=24, b=4)
// block 256, 4 l per thread, 8 c per block. Writes d_out directly (b,192,L).
// ---------------------------------------------------------------------------
__global__ __launch_bounds__(256) void k_outproj(const float* __restrict__ g,
                                                 const float* __restrict__ wout,
                                                 float* __restrict__ out) {
    __shared__ float wt[8 * DI];
    const int c0 = blockIdx.y * 8, b = blockIdx.z;
    const int l0 = blockIdx.x * 1024 + threadIdx.x * 4;
    for (int i = threadIdx.x; i < 8 * DI; i += 256)
        wt[i] = wout[(size_t)(c0 + i / DI) * DI + i % DI];
    __syncthreads();
    float acc[8][4];
#pragma unroll
    for (int cc = 0; cc < 8; ++cc) { acc[cc][0] = acc[cc][1] = acc[cc][2] = acc[cc][3] = 0.f; }
    const float* gb = g + (size_t)b * DI * LSEQ + l0;
    for (int d = 0; d < DI; d += 4) {
        float4 g0 = *(const float4*)(gb + (size_t)d * LSEQ);
        float4 g1 = *(const float4*)(gb + (size_t)(d + 1) * LSEQ);
        float4 g2 = *(const float4*)(gb + (size_t)(d + 2) * LSEQ);
        float4 g3 = *(const float4*)(gb + (size_t)(d + 3) * LSEQ);
#pragma unroll
        for (int cc = 0; cc < 8; ++cc) {
            float4 wv = *(const float4*)&wt[cc * DI + d];
            acc[cc][0] = fmaf(wv.x, g0.x, fmaf(wv.y, g1.x, fmaf(wv.z, g2.x, fmaf(wv.w, g3.x, acc[cc][0]))));
            acc[cc][1] = fmaf(wv.x, g0.y, fmaf(wv.y, g1.y, fmaf(wv.z, g2.y, fmaf(wv.w, g3.y, acc[cc][1]))));
            acc[cc][2] = fmaf(wv.x, g0.z, fmaf(wv.y, g1.z, fmaf(wv.z, g2.z, fmaf(wv.w, g3.z, acc[cc][2]))));
            acc[cc][3] = fmaf(wv.x, g0.w, fmaf(wv.y, g1.w, fmaf(wv.z, g2.w, fmaf(wv.w, g3.w, acc[cc][3]))));
        }
    }
#pragma unroll
    for (int cc = 0; cc < 8; ++cc) {
        float4 v = make_float4(acc[cc][0], acc[cc][1], acc[cc][2], acc[cc][3]);
        *(float4*)(out + ((size_t)b * CD + c0 + cc) * LSEQ + l0) = v;
    }
}

extern "C" void kernel_launch(void* const* d_in, const int* in_sizes, int n_in,
                              void* d_out, int out_size, void* d_ws, size_t ws_size,
                              hipStream_t stream) {
    const float* x     = (const float*)d_in[0];
    const float* w_in  = (const float*)d_in[1];
    const float* cw    = (const float*)d_in[2];
    const float* cb    = (const float*)d_in[3];
    const float* xpw   = (const float*)d_in[4];
    const float* dtw   = (const float*)d_in[5];
    const float* dtbv  = (const float*)d_in[6];
    const float* A_log = (const float*)d_in[7];
    const float* Dp    = (const float*)d_in[8];
    const float* wout  = (const float*)d_in[9];
    float* out = (float*)d_out;

    float* ws = (float*)d_ws;
    const size_t NBL = (size_t)BN * DI * LSEQ;            // 6,291,456 floats
    float* xp  = ws;                                      // (b,384,L)
    float* zs  = xp + NBL;                                // silu(z), (b,384,L)
    float* xc  = zs + NBL;                                // (b,384,L)
    float* dt  = xc + NBL;                                // (b,384,L)
    float* Bm  = dt + NBL;                                // (b,L,16)
    float* Cm  = Bm + (size_t)BN * LSEQ * DS;             // (b,L,16)
    float* dtr = Cm + (size_t)BN * LSEQ * DS;             // (b,12,L)
    float* xdp = dtr + (size_t)BN * DTRK * LSEQ;          // 4 parts x (b,44,L)
    float* g   = xp;                                      // reuse xp after conv

    k_inproj     <<<dim3(4, 48, BN), 256, 0, stream>>>(x, w_in, xp, zs);
    k_conv       <<<dim3(4, DI, BN), 256, 0, stream>>>(xp, cw, cb, xc);
    k_xdbl       <<<dim3(16, 4, BN), 256, 0, stream>>>(xc, xpw, xdp);
    k_xdbl_reduce<<<dim3(16, NJ, BN), 256, 0, stream>>>(xdp, dtr, Bm, Cm);
    k_dt         <<<dim3(16, 24, BN), 256, 0, stream>>>(dtr, dtw, dtbv, dt);
    k_scan       <<<dim3(DI, BN), 64, 0, stream>>>(dt, xc, Bm, Cm, zs, A_log, Dp, g);
    k_outproj    <<<dim3(4, 24, BN), 256, 0, stream>>>(g, wout, out);
}

// Round 2
// 494.465 us; speedup vs baseline: 1.3519x; 1.3519x over previous
//
#include <hip/hip_runtime.h>
#include <math.h>

#define BN   4
#define CD   192
#define LSEQ 4096
#define DI   384
#define DTRK 12
#define DS   16
#define NJ   44
#define NSPLIT 8          // L-segments per (b,d) row
#define SEG  512          // LSEQ / NSPLIT
#define CHK  8            // steps per thread (SEG / 64)

__device__ __forceinline__ float silu_f(float x) { return x / (1.f + __expf(-x)); }
__device__ __forceinline__ float softplus_f(float x) {
    return (x > 15.f) ? x : log1pf(__expf(x));
}

// ---------------------------------------------------------------------------
// K1: xz = in_proj(x).  x is (b, 192, L); out xp (b,384,L) and silu(z) (b,384,L)
// ---------------------------------------------------------------------------
__global__ __launch_bounds__(256) void k_inproj(const float* __restrict__ x,
                                                const float* __restrict__ w,
                                                float* __restrict__ xp,
                                                float* __restrict__ zs) {
    __shared__ float wt[16 * 192];
    const int b  = blockIdx.z;
    const int e0 = blockIdx.y * 16;
    const int l0 = blockIdx.x * 1024 + threadIdx.x * 4;
    for (int i = threadIdx.x; i < 16 * 192; i += 256) {
        int e = i / 192, c = i % 192;
        wt[i] = w[(size_t)(e0 + e) * 192 + c];
    }
    __syncthreads();
    float acc[16][4];
#pragma unroll
    for (int e = 0; e < 16; ++e) { acc[e][0] = acc[e][1] = acc[e][2] = acc[e][3] = 0.f; }
    const float* xb = x + (size_t)b * CD * LSEQ + l0;
    for (int c = 0; c < 192; c += 4) {
        float4 x0 = *(const float4*)(xb + (size_t)c * LSEQ);
        float4 x1 = *(const float4*)(xb + (size_t)(c + 1) * LSEQ);
        float4 x2 = *(const float4*)(xb + (size_t)(c + 2) * LSEQ);
        float4 x3 = *(const float4*)(xb + (size_t)(c + 3) * LSEQ);
#pragma unroll
        for (int e = 0; e < 16; ++e) {
            float4 wv = *(const float4*)&wt[e * 192 + c];
            acc[e][0] = fmaf(wv.x, x0.x, fmaf(wv.y, x1.x, fmaf(wv.z, x2.x, fmaf(wv.w, x3.x, acc[e][0]))));
            acc[e][1] = fmaf(wv.x, x0.y, fmaf(wv.y, x1.y, fmaf(wv.z, x2.y, fmaf(wv.w, x3.y, acc[e][1]))));
            acc[e][2] = fmaf(wv.x, x0.z, fmaf(wv.y, x1.z, fmaf(wv.z, x2.z, fmaf(wv.w, x3.z, acc[e][2]))));
            acc[e][3] = fmaf(wv.x, x0.w, fmaf(wv.y, x1.w, fmaf(wv.z, x2.w, fmaf(wv.w, x3.w, acc[e][3]))));
        }
    }
    const bool is_z = (e0 >= DI);
#pragma unroll
    for (int e = 0; e < 16; ++e) {
        float4 v = make_float4(acc[e][0], acc[e][1], acc[e][2], acc[e][3]);
        if (is_z) { v.x = silu_f(v.x); v.y = silu_f(v.y); v.z = silu_f(v.z); v.w = silu_f(v.w); }
        int row = is_z ? (e0 - DI + e) : (e0 + e);
        float* dst = (is_z ? zs : xp) + ((size_t)b * DI + row) * LSEQ + l0;
        *(float4*)dst = v;
    }
}

// ---------------------------------------------------------------------------
// K2: depthwise causal conv(4) + bias + silu.
// ---------------------------------------------------------------------------
__global__ __launch_bounds__(256) void k_conv(const float* __restrict__ xp,
                                              const float* __restrict__ cw,
                                              const float* __restrict__ cb,
                                              float* __restrict__ xc) {
    const int d = blockIdx.y, b = blockIdx.z;
    const int l0 = blockIdx.x * 1024 + threadIdx.x * 4;
    const float w0 = cw[d * 4 + 0], w1 = cw[d * 4 + 1], w2 = cw[d * 4 + 2], w3 = cw[d * 4 + 3];
    const float bb = cb[d];
    const float* row = xp + ((size_t)b * DI + d) * LSEQ;
    float4 cur = *(const float4*)(row + l0);
    float4 pv;
    if (l0 == 0) pv = make_float4(0.f, 0.f, 0.f, 0.f);
    else         pv = *(const float4*)(row + l0 - 4);
    float o0 = fmaf(w0, pv.y, fmaf(w1, pv.z, fmaf(w2, pv.w, fmaf(w3, cur.x, bb))));
    float o1 = fmaf(w0, pv.z, fmaf(w1, pv.w, fmaf(w2, cur.x, fmaf(w3, cur.y, bb))));
    float o2 = fmaf(w0, pv.w, fmaf(w1, cur.x, fmaf(w2, cur.y, fmaf(w3, cur.z, bb))));
    float o3 = fmaf(w0, cur.x, fmaf(w1, cur.y, fmaf(w2, cur.z, fmaf(w3, cur.w, bb))));
    float4 o = make_float4(silu_f(o0), silu_f(o1), silu_f(o2), silu_f(o3));
    *(float4*)(xc + ((size_t)b * DI + d) * LSEQ + l0) = o;
}

// ---------------------------------------------------------------------------
// K3a: x_dbl partials over d-partitions
// ---------------------------------------------------------------------------
__global__ __launch_bounds__(256) void k_xdbl(const float* __restrict__ xc,
                                              const float* __restrict__ xpw,
                                              float* __restrict__ xdp) {
    __shared__ float wt[NJ * 96];
    const int part = blockIdx.y, b = blockIdx.z;
    const int l = blockIdx.x * 256 + threadIdx.x;
    const int d0 = part * 96;
    for (int i = threadIdx.x; i < NJ * 96; i += 256) {
        int j = i / 96, dd = i % 96;
        wt[i] = xpw[(size_t)j * DI + d0 + dd];
    }
    __syncthreads();
    float acc[NJ];
#pragma unroll
    for (int j = 0; j < NJ; ++j) acc[j] = 0.f;
    const float* xcb = xc + ((size_t)b * DI + d0) * LSEQ + l;
    for (int dd = 0; dd < 96; dd += 4) {
        float v0 = xcb[(size_t)dd * LSEQ];
        float v1 = xcb[(size_t)(dd + 1) * LSEQ];
        float v2 = xcb[(size_t)(dd + 2) * LSEQ];
        float v3 = xcb[(size_t)(dd + 3) * LSEQ];
#pragma unroll
        for (int j = 0; j < NJ; ++j) {
            float4 wv = *(const float4*)&wt[j * 96 + dd];
            acc[j] = fmaf(wv.x, v0, fmaf(wv.y, v1, fmaf(wv.z, v2, fmaf(wv.w, v3, acc[j]))));
        }
    }
    float* dst = xdp + (size_t)(part * BN + b) * NJ * LSEQ + l;
#pragma unroll
    for (int j = 0; j < NJ; ++j) dst[(size_t)j * LSEQ] = acc[j];
}

// ---------------------------------------------------------------------------
// K3c: reduce partials; route rows to dtr / B / C
// ---------------------------------------------------------------------------
__global__ __launch_bounds__(256) void k_xdbl_reduce(const float* __restrict__ xdp,
                                                     float* __restrict__ dtr,
                                                     float* __restrict__ Bm,
                                                     float* __restrict__ Cm) {
    const int j = blockIdx.y, b = blockIdx.z;
    const int l = blockIdx.x * 256 + threadIdx.x;
    float s = 0.f;
#pragma unroll
    for (int p = 0; p < 4; ++p)
        s += xdp[(size_t)(p * BN + b) * NJ * LSEQ + (size_t)j * LSEQ + l];
    if (j < DTRK)            dtr[((size_t)b * DTRK + j) * LSEQ + l] = s;
    else if (j < DTRK + DS)  Bm[((size_t)b * LSEQ + l) * DS + (j - DTRK)] = s;
    else                     Cm[((size_t)b * LSEQ + l) * DS + (j - DTRK - DS)] = s;
}

// ---------------------------------------------------------------------------
// K3b: dt = softplus(dt_r @ dtw^T + dtb)
// ---------------------------------------------------------------------------
__global__ __launch_bounds__(256) void k_dt(const float* __restrict__ dtr,
                                            const float* __restrict__ dtw,
                                            const float* __restrict__ dtb,
                                            float* __restrict__ dt) {
    __shared__ float wt[16 * DTRK];
    __shared__ float bt[16];
    const int e0 = blockIdx.y * 16, b = blockIdx.z;
    const int l = blockIdx.x * 256 + threadIdx.x;
    if (threadIdx.x < 16 * DTRK)
        wt[threadIdx.x] = dtw[(size_t)(e0 + threadIdx.x / DTRK) * DTRK + threadIdx.x % DTRK];
    if (threadIdx.x < 16) bt[threadIdx.x] = dtb[e0 + threadIdx.x];
    __syncthreads();
    float acc[16];
#pragma unroll
    for (int e = 0; e < 16; ++e) acc[e] = 0.f;
    const float* rb = dtr + (size_t)b * DTRK * LSEQ + l;
#pragma unroll
    for (int r = 0; r < DTRK; ++r) {
        float v = rb[(size_t)r * LSEQ];
#pragma unroll
        for (int e = 0; e < 16; ++e) acc[e] = fmaf(wt[e * DTRK + r], v, acc[e]);
    }
    float* dst = dt + ((size_t)b * DI + e0) * LSEQ + l;
#pragma unroll
    for (int e = 0; e < 16; ++e) dst[(size_t)e * LSEQ] = softplus_f(acc[e] + bt[e]);
}

// ---------------------------------------------------------------------------
// K4a: scan pass 1 — local (P,H) aggregates per L-segment.
// grid (NSPLIT, DI, BN), block 64. Thread = 8-step chunk. LDS scan → block
// aggregate written to ws2[(bd*8+s)*32 + {0..15:P, 16..31:H}].
// ---------------------------------------------------------------------------
__global__ __launch_bounds__(64) void k_scan1(const float* __restrict__ dt,
                                              const float* __restrict__ xc,
                                              const float* __restrict__ Bm,
                                              const float* __restrict__ A_log,
                                              float* __restrict__ ws2) {
    __shared__ float sP[64][17];   // pad 17: write addr = ch*17+n → 2-way max
    __shared__ float sH[64][17];
    const int s = blockIdx.x, d = blockIdx.y, b = blockIdx.z;
    const int ch = threadIdx.x;
    const int bd = b * DI + d;
    float An[DS];
#pragma unroll
    for (int n = 0; n < DS; ++n) An[n] = -__expf(A_log[(size_t)d * DS + n]);
    const float* dtrow = dt + ((size_t)b * DI + d) * LSEQ + s * SEG;
    const float* xcrow = xc + ((size_t)b * DI + d) * LSEQ + s * SEG;
    const int l0 = ch * CHK;
    float4 da = *(const float4*)(dtrow + l0);
    float4 db = *(const float4*)(dtrow + l0 + 4);
    float4 xa = *(const float4*)(xcrow + l0);
    float4 xb = *(const float4*)(xcrow + l0 + 4);
    float dt8[8] = {da.x, da.y, da.z, da.w, db.x, db.y, db.z, db.w};
    float xc8[8] = {xa.x, xa.y, xa.z, xa.w, xb.x, xb.y, xb.z, xb.w};
    const float* Bbase = Bm + ((size_t)b * LSEQ + s * SEG + l0) * DS;

    float h[DS], p[DS];
#pragma unroll
    for (int n = 0; n < DS; ++n) { h[n] = 0.f; p[n] = 1.f; }
#pragma unroll
    for (int i = 0; i < CHK; ++i) {
        const float dtv = dt8[i];
        const float dx  = dtv * xc8[i];
        const float4* bp = (const float4*)(Bbase + (size_t)i * DS);
        float4 B0 = bp[0], B1 = bp[1], B2 = bp[2], B3 = bp[3];
        float Bv[DS] = {B0.x, B0.y, B0.z, B0.w, B1.x, B1.y, B1.z, B1.w,
                        B2.x, B2.y, B2.z, B2.w, B3.x, B3.y, B3.z, B3.w};
#pragma unroll
        for (int n = 0; n < DS; ++n) {
            float dA = __expf(dtv * An[n]);
            p[n] *= dA;
            h[n] = fmaf(dA, h[n], dx * Bv[n]);
        }
    }
#pragma unroll
    for (int n = 0; n < DS; ++n) { sP[ch][n] = p[n]; sH[ch][n] = h[n]; }
    __syncthreads();
    if (ch < DS) {
        float pc = 1.f, hc = 0.f;
        for (int c = 0; c < 64; ++c) {
            float pp = sP[c][ch];
            hc = fmaf(pp, hc, sH[c][ch]);
            pc *= pp;
        }
        float* w = ws2 + (size_t)(bd * NSPLIT + s) * 32;
        w[ch]      = pc;
        w[16 + ch] = hc;
    }
}

// ---------------------------------------------------------------------------
// K4b: scan the 8 segment aggregates per (b,d,n) → exclusive carry-in ws3.
// 24576 threads total.
// ---------------------------------------------------------------------------
__global__ __launch_bounds__(256) void k_scan2(const float* __restrict__ ws2,
                                               float* __restrict__ ws3) {
    const int t = blockIdx.x * 256 + threadIdx.x;   // (bd)*16 + n
    const int n = t & 15;
    const int bd = t >> 4;
    float hc = 0.f;
#pragma unroll
    for (int s = 0; s < NSPLIT; ++s) {
        const float* w = ws2 + (size_t)(bd * NSPLIT + s) * 32;
        float P = w[n], H = w[16 + n];
        ws3[(size_t)(bd * NSPLIT + s) * DS + n] = hc;
        hc = fmaf(P, hc, H);
    }
}

// ---------------------------------------------------------------------------
// K4c: scan pass 3 — replay with carry-in, y = sum_n h*C + D*xc, g = y*silu(z)
// ---------------------------------------------------------------------------
__global__ __launch_bounds__(64) void k_scan3(const float* __restrict__ dt,
                                              const float* __restrict__ xc,
                                              const float* __restrict__ Bm,
                                              const float* __restrict__ Cm,
                                              const float* __restrict__ zs,
                                              const float* __restrict__ A_log,
                                              const float* __restrict__ Dp,
                                              const float* __restrict__ ws3,
                                              float* __restrict__ g) {
    __shared__ float sP[64][17];
    __shared__ float sH[64][17];
    const int s = blockIdx.x, d = blockIdx.y, b = blockIdx.z;
    const int ch = threadIdx.x;
    const int bd = b * DI + d;
    float An[DS];
#pragma unroll
    for (int n = 0; n < DS; ++n) An[n] = -__expf(A_log[(size_t)d * DS + n]);
    const float Dd = Dp[d];
    const size_t rowoff = ((size_t)b * DI + d) * LSEQ + s * SEG;
    const float* dtrow = dt + rowoff;
    const float* xcrow = xc + rowoff;
    const float* zrow  = zs + rowoff;
    float*       grow  = g  + rowoff;
    const int l0 = ch * CHK;
    float4 da = *(const float4*)(dtrow + l0);
    float4 db = *(const float4*)(dtrow + l0 + 4);
    float4 xa = *(const float4*)(xcrow + l0);
    float4 xb = *(const float4*)(xcrow + l0 + 4);
    float4 za = *(const float4*)(zrow + l0);
    float4 zb = *(const float4*)(zrow + l0 + 4);
    float dt8[8] = {da.x, da.y, da.z, da.w, db.x, db.y, db.z, db.w};
    float xc8[8] = {xa.x, xa.y, xa.z, xa.w, xb.x, xb.y, xb.z, xb.w};
    float z8[8]  = {za.x, za.y, za.z, za.w, zb.x, zb.y, zb.z, zb.w};
    const size_t blc = ((size_t)b * LSEQ + s * SEG + l0) * DS;
    const float* Bbase = Bm + blc;
    const float* Cbase = Cm + blc;

    float h[DS], p[DS];
#pragma unroll
    for (int n = 0; n < DS; ++n) { h[n] = 0.f; p[n] = 1.f; }
#pragma unroll
    for (int i = 0; i < CHK; ++i) {
        const float dtv = dt8[i];
        const float dx  = dtv * xc8[i];
        const float4* bp = (const float4*)(Bbase + (size_t)i * DS);
        float4 B0 = bp[0], B1 = bp[1], B2 = bp[2], B3 = bp[3];
        float Bv[DS] = {B0.x, B0.y, B0.z, B0.w, B1.x, B1.y, B1.z, B1.w,
                        B2.x, B2.y, B2.z, B2.w, B3.x, B3.y, B3.z, B3.w};
#pragma unroll
        for (int n = 0; n < DS; ++n) {
            float dA = __expf(dtv * An[n]);
            p[n] *= dA;
            h[n] = fmaf(dA, h[n], dx * Bv[n]);
        }
    }
#pragma unroll
    for (int n = 0; n < DS; ++n) { sP[ch][n] = p[n]; sH[ch][n] = h[n]; }
    __syncthreads();
    if (ch < DS) {
        float hc = ws3[(size_t)(bd * NSPLIT + s) * DS + ch];
        for (int c = 0; c < 64; ++c) {
            float pp = sP[c][ch], hh = sH[c][ch];
            sP[c][ch] = hc;                 // exclusive carry-in for chunk c
            hc = fmaf(pp, hc, hh);
        }
    }
    __syncthreads();
#pragma unroll
    for (int n = 0; n < DS; ++n) h[n] = sP[ch][n];

    float out8[8];
#pragma unroll
    for (int i = 0; i < CHK; ++i) {
        const float dtv = dt8[i];
        const float xcv = xc8[i];
        const float dx  = dtv * xcv;
        const float4* bp = (const float4*)(Bbase + (size_t)i * DS);
        const float4* cp = (const float4*)(Cbase + (size_t)i * DS);
        float4 B0 = bp[0], B1 = bp[1], B2 = bp[2], B3 = bp[3];
        float4 C0 = cp[0], C1 = cp[1], C2 = cp[2], C3 = cp[3];
        float Bv[DS] = {B0.x, B0.y, B0.z, B0.w, B1.x, B1.y, B1.z, B1.w,
                        B2.x, B2.y, B2.z, B2.w, B3.x, B3.y, B3.z, B3.w};
        float Cv[DS] = {C0.x, C0.y, C0.z, C0.w, C1.x, C1.y, C1.z, C1.w,
                        C2.x, C2.y, C2.z, C2.w, C3.x, C3.y, C3.z, C3.w};
        float y = 0.f;
#pragma unroll
        for (int n = 0; n < DS; ++n) {
            float dA = __expf(dtv * An[n]);
            h[n] = fmaf(dA, h[n], dx * Bv[n]);
            y = fmaf(h[n], Cv[n], y);
        }
        out8[i] = (y + Dd * xcv) * z8[i];
    }
    *(float4*)(grow + l0)     = make_float4(out8[0], out8[1], out8[2], out8[3]);
    *(float4*)(grow + l0 + 4) = make_float4(out8[4], out8[5], out8[6], out8[7]);
}

// ---------------------------------------------------------------------------
// K5: out_proj
// ---------------------------------------------------------------------------
__global__ __launch_bounds__(256) void k_outproj(const float* __restrict__ g,
                                                 const float* __restrict__ wout,
                                                 float* __restrict__ out) {
    __shared__ float wt[8 * DI];
    const int c0 = blockIdx.y * 8, b = blockIdx.z;
    const int l0 = blockIdx.x * 1024 + threadIdx.x * 4;
    for (int i = threadIdx.x; i < 8 * DI; i += 256)
        wt[i] = wout[(size_t)(c0 + i / DI) * DI + i % DI];
    __syncthreads();
    float acc[8][4];
#pragma unroll
    for (int cc = 0; cc < 8; ++cc) { acc[cc][0] = acc[cc][1] = acc[cc][2] = acc[cc][3] = 0.f; }
    const float* gb = g + (size_t)b * DI * LSEQ + l0;
    for (int d = 0; d < DI; d += 4) {
        float4 g0 = *(const float4*)(gb + (size_t)d * LSEQ);
        float4 g1 = *(const float4*)(gb + (size_t)(d + 1) * LSEQ);
        float4 g2 = *(const float4*)(gb + (size_t)(d + 2) * LSEQ);
        float4 g3 = *(const float4*)(gb + (size_t)(d + 3) * LSEQ);
#pragma unroll
        for (int cc = 0; cc < 8; ++cc) {
            float4 wv = *(const float4*)&wt[cc * DI + d];
            acc[cc][0] = fmaf(wv.x, g0.x, fmaf(wv.y, g1.x, fmaf(wv.z, g2.x, fmaf(wv.w, g3.x, acc[cc][0]))));
            acc[cc][1] = fmaf(wv.x, g0.y, fmaf(wv.y, g1.y, fmaf(wv.z, g2.y, fmaf(wv.w, g3.y, acc[cc][1]))));
            acc[cc][2] = fmaf(wv.x, g0.z, fmaf(wv.y, g1.z, fmaf(wv.z, g2.z, fmaf(wv.w, g3.z, acc[cc][2]))));
            acc[cc][3] = fmaf(wv.x, g0.w, fmaf(wv.y, g1.w, fmaf(wv.z, g2.w, fmaf(wv.w, g3.w, acc[cc][3]))));
        }
    }
#pragma unroll
    for (int cc = 0; cc < 8; ++cc) {
        float4 v = make_float4(acc[cc][0], acc[cc][1], acc[cc][2], acc[cc][3]);
        *(float4*)(out + ((size_t)b * CD + c0 + cc) * LSEQ + l0) = v;
    }
}

extern "C" void kernel_launch(void* const* d_in, const int* in_sizes, int n_in,
                              void* d_out, int out_size, void* d_ws, size_t ws_size,
                              hipStream_t stream) {
    const float* x     = (const float*)d_in[0];
    const float* w_in  = (const float*)d_in[1];
    const float* cw    = (const float*)d_in[2];
    const float* cb    = (const float*)d_in[3];
    const float* xpw   = (const float*)d_in[4];
    const float* dtw   = (const float*)d_in[5];
    const float* dtbv  = (const float*)d_in[6];
    const float* A_log = (const float*)d_in[7];
    const float* Dp    = (const float*)d_in[8];
    const float* wout  = (const float*)d_in[9];
    float* out = (float*)d_out;

    float* ws = (float*)d_ws;
    const size_t NBL = (size_t)BN * DI * LSEQ;            // 6,291,456 floats
    float* xp  = ws;                                      // (b,384,L)
    float* zs  = xp + NBL;                                // silu(z)
    float* xc  = zs + NBL;                                // conv out
    float* dt  = xc + NBL;                                // softplus dt
    float* Bm  = dt + NBL;                                // (b,L,16)
    float* Cm  = Bm + (size_t)BN * LSEQ * DS;             // (b,L,16)
    float* dtr = Cm + (size_t)BN * LSEQ * DS;             // (b,12,L)
    float* xdp = dtr + (size_t)BN * DTRK * LSEQ;          // 4 x (b,44,L); dead after k_dt
    float* g   = xp;                                      // reuse xp after conv
    // scan scratch lives in the dead xdp region (needs 2.3 MB < 11.5 MB):
    float* ws2 = xdp;                                     // 12288 * 32 floats
    float* ws3 = ws2 + (size_t)BN * DI * NSPLIT * 32;     // 12288 * 16 floats

    k_inproj     <<<dim3(4, 48, BN), 256, 0, stream>>>(x, w_in, xp, zs);
    k_conv       <<<dim3(4, DI, BN), 256, 0, stream>>>(xp, cw, cb, xc);
    k_xdbl       <<<dim3(16, 4, BN), 256, 0, stream>>>(xc, xpw, xdp);
    k_xdbl_reduce<<<dim3(16, NJ, BN), 256, 0, stream>>>(xdp, dtr, Bm, Cm);
    k_dt         <<<dim3(16, 24, BN), 256, 0, stream>>>(dtr, dtw, dtbv, dt);
    k_scan1      <<<dim3(NSPLIT, DI, BN), 64, 0, stream>>>(dt, xc, Bm, A_log, ws2);
    k_scan2      <<<dim3(96), 256, 0, stream>>>(ws2, ws3);
    k_scan3      <<<dim3(NSPLIT, DI, BN), 64, 0, stream>>>(dt, xc, Bm, Cm, zs, A_log, Dp, ws3, g);
    k_outproj    <<<dim3(4, 24, BN), 256, 0, stream>>>(g, wout, out);
}

// Round 3
// 373.053 us; speedup vs baseline: 1.7919x; 1.3255x over previous
//
#include <hip/hip_runtime.h>
#include <math.h>

#define BN   4
#define CD   192
#define LSEQ 4096
#define DI   384
#define DTRK 12
#define DS   16
#define NJ   44
#define NSPLIT 8          // L-segments per (b,d) row
#define SEG  512          // LSEQ / NSPLIT
#define CHK  8            // steps per thread (SEG / 64)

__device__ __forceinline__ float silu_f(float x) { return x / (1.f + __expf(-x)); }
__device__ __forceinline__ float softplus_f(float x) {
    return (x > 15.f) ? x : log1pf(__expf(x));
}

// Inclusive Hillis-Steele scan of affine elements (P,H) across the 64-lane
// wave.  Element at lane i represents h -> P*h + H for chunk i; scan composes
// chunks 0..lane in order.
__device__ __forceinline__ void wave_scan_ph(float& P, float& H, int lane) {
#pragma unroll
    for (int delta = 1; delta < 64; delta <<= 1) {
        float Pp = __shfl_up(P, (unsigned)delta);
        float Hp = __shfl_up(H, (unsigned)delta);
        bool v = (lane >= delta);
        Pp = v ? Pp : 1.0f;
        Hp = v ? Hp : 0.0f;
        H = fmaf(P, Hp, H);   // uses pre-update P
        P *= Pp;
    }
}

// ---------------------------------------------------------------------------
// K1: xz = in_proj(x).  x is (b, 192, L); out xp (b,384,L) and silu(z) (b,384,L)
// ---------------------------------------------------------------------------
__global__ __launch_bounds__(256) void k_inproj(const float* __restrict__ x,
                                                const float* __restrict__ w,
                                                float* __restrict__ xp,
                                                float* __restrict__ zs) {
    __shared__ float wt[16 * 192];
    const int b  = blockIdx.z;
    const int e0 = blockIdx.y * 16;
    const int l0 = blockIdx.x * 1024 + threadIdx.x * 4;
    for (int i = threadIdx.x; i < 16 * 192; i += 256) {
        int e = i / 192, c = i % 192;
        wt[i] = w[(size_t)(e0 + e) * 192 + c];
    }
    __syncthreads();
    float acc[16][4];
#pragma unroll
    for (int e = 0; e < 16; ++e) { acc[e][0] = acc[e][1] = acc[e][2] = acc[e][3] = 0.f; }
    const float* xb = x + (size_t)b * CD * LSEQ + l0;
    for (int c = 0; c < 192; c += 4) {
        float4 x0 = *(const float4*)(xb + (size_t)c * LSEQ);
        float4 x1 = *(const float4*)(xb + (size_t)(c + 1) * LSEQ);
        float4 x2 = *(const float4*)(xb + (size_t)(c + 2) * LSEQ);
        float4 x3 = *(const float4*)(xb + (size_t)(c + 3) * LSEQ);
#pragma unroll
        for (int e = 0; e < 16; ++e) {
            float4 wv = *(const float4*)&wt[e * 192 + c];
            acc[e][0] = fmaf(wv.x, x0.x, fmaf(wv.y, x1.x, fmaf(wv.z, x2.x, fmaf(wv.w, x3.x, acc[e][0]))));
            acc[e][1] = fmaf(wv.x, x0.y, fmaf(wv.y, x1.y, fmaf(wv.z, x2.y, fmaf(wv.w, x3.y, acc[e][1]))));
            acc[e][2] = fmaf(wv.x, x0.z, fmaf(wv.y, x1.z, fmaf(wv.z, x2.z, fmaf(wv.w, x3.z, acc[e][2]))));
            acc[e][3] = fmaf(wv.x, x0.w, fmaf(wv.y, x1.w, fmaf(wv.z, x2.w, fmaf(wv.w, x3.w, acc[e][3]))));
        }
    }
    const bool is_z = (e0 >= DI);
#pragma unroll
    for (int e = 0; e < 16; ++e) {
        float4 v = make_float4(acc[e][0], acc[e][1], acc[e][2], acc[e][3]);
        if (is_z) { v.x = silu_f(v.x); v.y = silu_f(v.y); v.z = silu_f(v.z); v.w = silu_f(v.w); }
        int row = is_z ? (e0 - DI + e) : (e0 + e);
        float* dst = (is_z ? zs : xp) + ((size_t)b * DI + row) * LSEQ + l0;
        *(float4*)dst = v;
    }
}

// ---------------------------------------------------------------------------
// K2: depthwise causal conv(4) + bias + silu.
// ---------------------------------------------------------------------------
__global__ __launch_bounds__(256) void k_conv(const float* __restrict__ xp,
                                              const float* __restrict__ cw,
                                              const float* __restrict__ cb,
                                              float* __restrict__ xc) {
    const int d = blockIdx.y, b = blockIdx.z;
    const int l0 = blockIdx.x * 1024 + threadIdx.x * 4;
    const float w0 = cw[d * 4 + 0], w1 = cw[d * 4 + 1], w2 = cw[d * 4 + 2], w3 = cw[d * 4 + 3];
    const float bb = cb[d];
    const float* row = xp + ((size_t)b * DI + d) * LSEQ;
    float4 cur = *(const float4*)(row + l0);
    float4 pv;
    if (l0 == 0) pv = make_float4(0.f, 0.f, 0.f, 0.f);
    else         pv = *(const float4*)(row + l0 - 4);
    float o0 = fmaf(w0, pv.y, fmaf(w1, pv.z, fmaf(w2, pv.w, fmaf(w3, cur.x, bb))));
    float o1 = fmaf(w0, pv.z, fmaf(w1, pv.w, fmaf(w2, cur.x, fmaf(w3, cur.y, bb))));
    float o2 = fmaf(w0, pv.w, fmaf(w1, cur.x, fmaf(w2, cur.y, fmaf(w3, cur.z, bb))));
    float o3 = fmaf(w0, cur.x, fmaf(w1, cur.y, fmaf(w2, cur.z, fmaf(w3, cur.w, bb))));
    float4 o = make_float4(silu_f(o0), silu_f(o1), silu_f(o2), silu_f(o3));
    *(float4*)(xc + ((size_t)b * DI + d) * LSEQ + l0) = o;
}

// ---------------------------------------------------------------------------
// K3a: x_dbl partials over d-partitions
// ---------------------------------------------------------------------------
__global__ __launch_bounds__(256) void k_xdbl(const float* __restrict__ xc,
                                              const float* __restrict__ xpw,
                                              float* __restrict__ xdp) {
    __shared__ float wt[NJ * 96];
    const int part = blockIdx.y, b = blockIdx.z;
    const int l = blockIdx.x * 256 + threadIdx.x;
    const int d0 = part * 96;
    for (int i = threadIdx.x; i < NJ * 96; i += 256) {
        int j = i / 96, dd = i % 96;
        wt[i] = xpw[(size_t)j * DI + d0 + dd];
    }
    __syncthreads();
    float acc[NJ];
#pragma unroll
    for (int j = 0; j < NJ; ++j) acc[j] = 0.f;
    const float* xcb = xc + ((size_t)b * DI + d0) * LSEQ + l;
    for (int dd = 0; dd < 96; dd += 4) {
        float v0 = xcb[(size_t)dd * LSEQ];
        float v1 = xcb[(size_t)(dd + 1) * LSEQ];
        float v2 = xcb[(size_t)(dd + 2) * LSEQ];
        float v3 = xcb[(size_t)(dd + 3) * LSEQ];
#pragma unroll
        for (int j = 0; j < NJ; ++j) {
            float4 wv = *(const float4*)&wt[j * 96 + dd];
            acc[j] = fmaf(wv.x, v0, fmaf(wv.y, v1, fmaf(wv.z, v2, fmaf(wv.w, v3, acc[j]))));
        }
    }
    float* dst = xdp + (size_t)(part * BN + b) * NJ * LSEQ + l;
#pragma unroll
    for (int j = 0; j < NJ; ++j) dst[(size_t)j * LSEQ] = acc[j];
}

// ---------------------------------------------------------------------------
// K3c: reduce partials; route rows to dtr / B_t / C_t.
// B_t, C_t layouts are (b, n, L) so the scan reads them coalesced.
// ---------------------------------------------------------------------------
__global__ __launch_bounds__(256) void k_xdbl_reduce(const float* __restrict__ xdp,
                                                     float* __restrict__ dtr,
                                                     float* __restrict__ Bm,
                                                     float* __restrict__ Cm) {
    const int j = blockIdx.y, b = blockIdx.z;
    const int l = blockIdx.x * 256 + threadIdx.x;
    float s = 0.f;
#pragma unroll
    for (int p = 0; p < 4; ++p)
        s += xdp[(size_t)(p * BN + b) * NJ * LSEQ + (size_t)j * LSEQ + l];
    if (j < DTRK)            dtr[((size_t)b * DTRK + j) * LSEQ + l] = s;
    else if (j < DTRK + DS)  Bm[((size_t)b * DS + (j - DTRK)) * LSEQ + l] = s;
    else                     Cm[((size_t)b * DS + (j - DTRK - DS)) * LSEQ + l] = s;
}

// ---------------------------------------------------------------------------
// K3b: dt = softplus(dt_r @ dtw^T + dtb)
// ---------------------------------------------------------------------------
__global__ __launch_bounds__(256) void k_dt(const float* __restrict__ dtr,
                                            const float* __restrict__ dtw,
                                            const float* __restrict__ dtb,
                                            float* __restrict__ dt) {
    __shared__ float wt[16 * DTRK];
    __shared__ float bt[16];
    const int e0 = blockIdx.y * 16, b = blockIdx.z;
    const int l = blockIdx.x * 256 + threadIdx.x;
    if (threadIdx.x < 16 * DTRK)
        wt[threadIdx.x] = dtw[(size_t)(e0 + threadIdx.x / DTRK) * DTRK + threadIdx.x % DTRK];
    if (threadIdx.x < 16) bt[threadIdx.x] = dtb[e0 + threadIdx.x];
    __syncthreads();
    float acc[16];
#pragma unroll
    for (int e = 0; e < 16; ++e) acc[e] = 0.f;
    const float* rb = dtr + (size_t)b * DTRK * LSEQ + l;
#pragma unroll
    for (int r = 0; r < DTRK; ++r) {
        float v = rb[(size_t)r * LSEQ];
#pragma unroll
        for (int e = 0; e < 16; ++e) acc[e] = fmaf(wt[e * DTRK + r], v, acc[e]);
    }
    float* dst = dt + ((size_t)b * DI + e0) * LSEQ + l;
#pragma unroll
    for (int e = 0; e < 16; ++e) dst[(size_t)e * LSEQ] = softplus_f(acc[e] + bt[e]);
}

// ---------------------------------------------------------------------------
// K4a: scan pass 1 — per-segment (P,H) aggregates, n-outer, shuffle scan.
// block 256 = 4 independent waves; wave w handles segment blockIdx.x*4+w of
// row (b,d). Lane = 8-step chunk.  No LDS.
// ---------------------------------------------------------------------------
__global__ __launch_bounds__(256) void k_scan1(const float* __restrict__ dt,
                                               const float* __restrict__ xc,
                                               const float* __restrict__ Bm,
                                               const float* __restrict__ A_log,
                                               float* __restrict__ ws2) {
    const int lane = threadIdx.x & 63;
    const int s = blockIdx.x * 4 + (threadIdx.x >> 6);
    const int d = blockIdx.y, b = blockIdx.z;
    const int bd = b * DI + d;
    const size_t rowoff = ((size_t)b * DI + d) * LSEQ + s * SEG;
    const int l0 = lane * CHK;
    float4 da = *(const float4*)(dt + rowoff + l0);
    float4 db = *(const float4*)(dt + rowoff + l0 + 4);
    float4 xa = *(const float4*)(xc + rowoff + l0);
    float4 xb = *(const float4*)(xc + rowoff + l0 + 4);
    float dt8[8] = {da.x, da.y, da.z, da.w, db.x, db.y, db.z, db.w};
    float dx8[8] = {da.x * xa.x, da.y * xa.y, da.z * xa.z, da.w * xa.w,
                    db.x * xb.x, db.y * xb.y, db.z * xb.z, db.w * xb.w};
    const float* Alogd = A_log + (size_t)d * DS;
    float* wout = ws2 + (size_t)(bd * NSPLIT + s) * 32;

    for (int n = 0; n < DS; ++n) {
        const float An = -__expf(Alogd[n]);
        const float* Bn = Bm + ((size_t)(b * DS + n)) * LSEQ + s * SEG + l0;
        float4 Ba = *(const float4*)Bn;
        float4 Bb = *(const float4*)(Bn + 4);
        float B8[8] = {Ba.x, Ba.y, Ba.z, Ba.w, Bb.x, Bb.y, Bb.z, Bb.w};
        float p = 1.f, h = 0.f;
#pragma unroll
        for (int i = 0; i < CHK; ++i) {
            float dA = __expf(dt8[i] * An);
            h = fmaf(dA, h, dx8[i] * B8[i]);
            p *= dA;
        }
        wave_scan_ph(p, h, lane);
        if (lane == 63) { wout[n] = p; wout[16 + n] = h; }
    }
}

// ---------------------------------------------------------------------------
// K4b: scan the 8 segment aggregates per (b,d,n) → exclusive carry-in ws3.
// ---------------------------------------------------------------------------
__global__ __launch_bounds__(256) void k_scan2(const float* __restrict__ ws2,
                                               float* __restrict__ ws3) {
    const int t = blockIdx.x * 256 + threadIdx.x;   // (bd)*16 + n
    const int n = t & 15;
    const int bd = t >> 4;
    float hc = 0.f;
#pragma unroll
    for (int s = 0; s < NSPLIT; ++s) {
        const float* w = ws2 + (size_t)(bd * NSPLIT + s) * 32;
        float P = w[n], H = w[16 + n];
        ws3[(size_t)(bd * NSPLIT + s) * DS + n] = hc;
        hc = fmaf(P, hc, H);
    }
}

// ---------------------------------------------------------------------------
// K4c: scan pass 3 — n-outer, shuffle scan for intra-segment carries, replay
// accumulating y, then gate.  No LDS.
// ---------------------------------------------------------------------------
__global__ __launch_bounds__(256) void k_scan3(const float* __restrict__ dt,
                                               const float* __restrict__ xc,
                                               const float* __restrict__ Bm,
                                               const float* __restrict__ Cm,
                                               const float* __restrict__ zs,
                                               const float* __restrict__ A_log,
                                               const float* __restrict__ Dp,
                                               const float* __restrict__ ws3,
                                               float* __restrict__ g) {
    const int lane = threadIdx.x & 63;
    const int s = blockIdx.x * 4 + (threadIdx.x >> 6);
    const int d = blockIdx.y, b = blockIdx.z;
    const int bd = b * DI + d;
    const size_t rowoff = ((size_t)b * DI + d) * LSEQ + s * SEG;
    const int l0 = lane * CHK;
    float4 da = *(const float4*)(dt + rowoff + l0);
    float4 db = *(const float4*)(dt + rowoff + l0 + 4);
    float4 xa = *(const float4*)(xc + rowoff + l0);
    float4 xb = *(const float4*)(xc + rowoff + l0 + 4);
    float4 za = *(const float4*)(zs + rowoff + l0);
    float4 zb = *(const float4*)(zs + rowoff + l0 + 4);
    float dt8[8] = {da.x, da.y, da.z, da.w, db.x, db.y, db.z, db.w};
    float xc8[8] = {xa.x, xa.y, xa.z, xa.w, xb.x, xb.y, xb.z, xb.w};
    float z8[8]  = {za.x, za.y, za.z, za.w, zb.x, zb.y, zb.z, zb.w};
    float dx8[8];
#pragma unroll
    for (int i = 0; i < CHK; ++i) dx8[i] = dt8[i] * xc8[i];
    float y8[8] = {0.f, 0.f, 0.f, 0.f, 0.f, 0.f, 0.f, 0.f};
    const float* Alogd = A_log + (size_t)d * DS;
    const float* carry = ws3 + (size_t)(bd * NSPLIT + s) * DS;

    for (int n = 0; n < DS; ++n) {
        const float An = -__expf(Alogd[n]);
        const size_t nloff = ((size_t)(b * DS + n)) * LSEQ + s * SEG + l0;
        float4 Ba = *(const float4*)(Bm + nloff);
        float4 Bb = *(const float4*)(Bm + nloff + 4);
        float4 Ca = *(const float4*)(Cm + nloff);
        float4 Cb = *(const float4*)(Cm + nloff + 4);
        float B8[8] = {Ba.x, Ba.y, Ba.z, Ba.w, Bb.x, Bb.y, Bb.z, Bb.w};
        float C8[8] = {Ca.x, Ca.y, Ca.z, Ca.w, Cb.x, Cb.y, Cb.z, Cb.w};
        float dA8[8];
        float p = 1.f, h = 0.f;
#pragma unroll
        for (int i = 0; i < CHK; ++i) {
            float dA = __expf(dt8[i] * An);
            dA8[i] = dA;
            h = fmaf(dA, h, dx8[i] * B8[i]);
            p *= dA;
        }
        wave_scan_ph(p, h, lane);
        // exclusive prefix for this lane
        float Pe = __shfl_up(p, 1u);
        float He = __shfl_up(h, 1u);
        if (lane == 0) { Pe = 1.f; He = 0.f; }
        float hv = fmaf(Pe, carry[n], He);   // h entering this lane's chunk
#pragma unroll
        for (int i = 0; i < CHK; ++i) {
            hv = fmaf(dA8[i], hv, dx8[i] * B8[i]);
            y8[i] = fmaf(hv, C8[i], y8[i]);
        }
    }
    const float Dd = Dp[d];
    float out8[8];
#pragma unroll
    for (int i = 0; i < CHK; ++i) out8[i] = fmaf(Dd, xc8[i], y8[i]) * z8[i];
    float* grow = g + rowoff;
    *(float4*)(grow + l0)     = make_float4(out8[0], out8[1], out8[2], out8[3]);
    *(float4*)(grow + l0 + 4) = make_float4(out8[4], out8[5], out8[6], out8[7]);
}

// ---------------------------------------------------------------------------
// K5: out_proj
// ---------------------------------------------------------------------------
__global__ __launch_bounds__(256) void k_outproj(const float* __restrict__ g,
                                                 const float* __restrict__ wout,
                                                 float* __restrict__ out) {
    __shared__ float wt[8 * DI];
    const int c0 = blockIdx.y * 8, b = blockIdx.z;
    const int l0 = blockIdx.x * 1024 + threadIdx.x * 4;
    for (int i = threadIdx.x; i < 8 * DI; i += 256)
        wt[i] = wout[(size_t)(c0 + i / DI) * DI + i % DI];
    __syncthreads();
    float acc[8][4];
#pragma unroll
    for (int cc = 0; cc < 8; ++cc) { acc[cc][0] = acc[cc][1] = acc[cc][2] = acc[cc][3] = 0.f; }
    const float* gb = g + (size_t)b * DI * LSEQ + l0;
    for (int d = 0; d < DI; d += 4) {
        float4 g0 = *(const float4*)(gb + (size_t)d * LSEQ);
        float4 g1 = *(const float4*)(gb + (size_t)(d + 1) * LSEQ);
        float4 g2 = *(const float4*)(gb + (size_t)(d + 2) * LSEQ);
        float4 g3 = *(const float4*)(gb + (size_t)(d + 3) * LSEQ);
#pragma unroll
        for (int cc = 0; cc < 8; ++cc) {
            float4 wv = *(const float4*)&wt[cc * DI + d];
            acc[cc][0] = fmaf(wv.x, g0.x, fmaf(wv.y, g1.x, fmaf(wv.z, g2.x, fmaf(wv.w, g3.x, acc[cc][0]))));
            acc[cc][1] = fmaf(wv.x, g0.y, fmaf(wv.y, g1.y, fmaf(wv.z, g2.y, fmaf(wv.w, g3.y, acc[cc][1]))));
            acc[cc][2] = fmaf(wv.x, g0.z, fmaf(wv.y, g1.z, fmaf(wv.z, g2.z, fmaf(wv.w, g3.z, acc[cc][2]))));
            acc[cc][3] = fmaf(wv.x, g0.w, fmaf(wv.y, g1.w, fmaf(wv.z, g2.w, fmaf(wv.w, g3.w, acc[cc][3]))));
        }
    }
#pragma unroll
    for (int cc = 0; cc < 8; ++cc) {
        float4 v = make_float4(acc[cc][0], acc[cc][1], acc[cc][2], acc[cc][3]);
        *(float4*)(out + ((size_t)b * CD + c0 + cc) * LSEQ + l0) = v;
    }
}

extern "C" void kernel_launch(void* const* d_in, const int* in_sizes, int n_in,
                              void* d_out, int out_size, void* d_ws, size_t ws_size,
                              hipStream_t stream) {
    const float* x     = (const float*)d_in[0];
    const float* w_in  = (const float*)d_in[1];
    const float* cw    = (const float*)d_in[2];
    const float* cb    = (const float*)d_in[3];
    const float* xpw   = (const float*)d_in[4];
    const float* dtw   = (const float*)d_in[5];
    const float* dtbv  = (const float*)d_in[6];
    const float* A_log = (const float*)d_in[7];
    const float* Dp    = (const float*)d_in[8];
    const float* wout  = (const float*)d_in[9];
    float* out = (float*)d_out;

    float* ws = (float*)d_ws;
    const size_t NBL = (size_t)BN * DI * LSEQ;            // 6,291,456 floats
    float* xp  = ws;                                      // (b,384,L)
    float* zs  = xp + NBL;                                // silu(z)
    float* xc  = zs + NBL;                                // conv out
    float* dt  = xc + NBL;                                // softplus dt
    float* Bm  = dt + NBL;                                // (b,16,L) transposed
    float* Cm  = Bm + (size_t)BN * LSEQ * DS;             // (b,16,L) transposed
    float* dtr = Cm + (size_t)BN * LSEQ * DS;             // (b,12,L)
    float* xdp = dtr + (size_t)BN * DTRK * LSEQ;          // 4 x (b,44,L); dead after k_dt
    float* g   = xp;                                      // reuse xp after conv
    float* ws2 = xdp;                                     // 12288 * 32 floats
    float* ws3 = ws2 + (size_t)BN * DI * NSPLIT * 32;     // 12288 * 16 floats

    k_inproj     <<<dim3(4, 48, BN), 256, 0, stream>>>(x, w_in, xp, zs);
    k_conv       <<<dim3(4, DI, BN), 256, 0, stream>>>(xp, cw, cb, xc);
    k_xdbl       <<<dim3(16, 4, BN), 256, 0, stream>>>(xc, xpw, xdp);
    k_xdbl_reduce<<<dim3(16, NJ, BN), 256, 0, stream>>>(xdp, dtr, Bm, Cm);
    k_dt         <<<dim3(16, 24, BN), 256, 0, stream>>>(dtr, dtw, dtbv, dt);
    k_scan1      <<<dim3(NSPLIT / 4, DI, BN), 256, 0, stream>>>(dt, xc, Bm, A_log, ws2);
    k_scan2      <<<dim3(96), 256, 0, stream>>>(ws2, ws3);
    k_scan3      <<<dim3(NSPLIT / 4, DI, BN), 256, 0, stream>>>(dt, xc, Bm, Cm, zs, A_log, Dp, ws3, g);
    k_outproj    <<<dim3(4, 24, BN), 256, 0, stream>>>(g, wout, out);
}

// Round 4
// 350.765 us; speedup vs baseline: 1.9058x; 1.0635x over previous
//
#include <hip/hip_runtime.h>
#include <math.h>

#define BN   4
#define CD   192
#define LSEQ 4096
#define DI   384
#define DTRK 12
#define DS   16
#define NJ   44
#define NSPLIT 8          // L-segments per (b,d) row
#define SEG  512          // LSEQ / NSPLIT
#define CHK  8            // steps per thread (SEG / 64)

__device__ __forceinline__ float silu_f(float x) { return x / (1.f + __expf(-x)); }
__device__ __forceinline__ float softplus_f(float x) {
    return (x > 15.f) ? x : log1pf(__expf(x));
}

// Inclusive Hillis-Steele scan of affine elements (P,H) across the 64-lane wave.
__device__ __forceinline__ void wave_scan_ph(float& P, float& H, int lane) {
#pragma unroll
    for (int delta = 1; delta < 64; delta <<= 1) {
        float Pp = __shfl_up(P, (unsigned)delta);
        float Hp = __shfl_up(H, (unsigned)delta);
        bool v = (lane >= delta);
        Pp = v ? Pp : 1.0f;
        Hp = v ? Hp : 0.0f;
        H = fmaf(P, Hp, H);   // uses pre-update P
        P *= Pp;
    }
}

// ---------------------------------------------------------------------------
// K1: in_proj.  grid (8, 48, BN), 2 l per thread (float2) -> 24 waves/CU.
// ---------------------------------------------------------------------------
__global__ __launch_bounds__(256) void k_inproj(const float* __restrict__ x,
                                                const float* __restrict__ w,
                                                float* __restrict__ xp,
                                                float* __restrict__ zs) {
    __shared__ float wt[16 * 192];
    const int b  = blockIdx.z;
    const int e0 = blockIdx.y * 16;
    const int l0 = blockIdx.x * 512 + threadIdx.x * 2;
    for (int i = threadIdx.x; i < 16 * 192; i += 256) {
        int e = i / 192, c = i % 192;
        wt[i] = w[(size_t)(e0 + e) * 192 + c];
    }
    __syncthreads();
    float acc[16][2];
#pragma unroll
    for (int e = 0; e < 16; ++e) { acc[e][0] = acc[e][1] = 0.f; }
    const float* xb = x + (size_t)b * CD * LSEQ + l0;
    for (int c = 0; c < 192; c += 4) {
        float2 x0 = *(const float2*)(xb + (size_t)c * LSEQ);
        float2 x1 = *(const float2*)(xb + (size_t)(c + 1) * LSEQ);
        float2 x2 = *(const float2*)(xb + (size_t)(c + 2) * LSEQ);
        float2 x3 = *(const float2*)(xb + (size_t)(c + 3) * LSEQ);
#pragma unroll
        for (int e = 0; e < 16; ++e) {
            float4 wv = *(const float4*)&wt[e * 192 + c];
            acc[e][0] = fmaf(wv.x, x0.x, fmaf(wv.y, x1.x, fmaf(wv.z, x2.x, fmaf(wv.w, x3.x, acc[e][0]))));
            acc[e][1] = fmaf(wv.x, x0.y, fmaf(wv.y, x1.y, fmaf(wv.z, x2.y, fmaf(wv.w, x3.y, acc[e][1]))));
        }
    }
    const bool is_z = (e0 >= DI);
#pragma unroll
    for (int e = 0; e < 16; ++e) {
        float2 v = make_float2(acc[e][0], acc[e][1]);
        if (is_z) { v.x = silu_f(v.x); v.y = silu_f(v.y); }
        int row = is_z ? (e0 - DI + e) : (e0 + e);
        float* dst = (is_z ? zs : xp) + ((size_t)b * DI + row) * LSEQ + l0;
        *(float2*)dst = v;
    }
}

// ---------------------------------------------------------------------------
// K2: depthwise causal conv(4) + bias + silu.
// ---------------------------------------------------------------------------
__global__ __launch_bounds__(256) void k_conv(const float* __restrict__ xp,
                                              const float* __restrict__ cw,
                                              const float* __restrict__ cb,
                                              float* __restrict__ xc) {
    const int d = blockIdx.y, b = blockIdx.z;
    const int l0 = blockIdx.x * 1024 + threadIdx.x * 4;
    const float w0 = cw[d * 4 + 0], w1 = cw[d * 4 + 1], w2 = cw[d * 4 + 2], w3 = cw[d * 4 + 3];
    const float bb = cb[d];
    const float* row = xp + ((size_t)b * DI + d) * LSEQ;
    float4 cur = *(const float4*)(row + l0);
    float4 pv;
    if (l0 == 0) pv = make_float4(0.f, 0.f, 0.f, 0.f);
    else         pv = *(const float4*)(row + l0 - 4);
    float o0 = fmaf(w0, pv.y, fmaf(w1, pv.z, fmaf(w2, pv.w, fmaf(w3, cur.x, bb))));
    float o1 = fmaf(w0, pv.z, fmaf(w1, pv.w, fmaf(w2, cur.x, fmaf(w3, cur.y, bb))));
    float o2 = fmaf(w0, pv.w, fmaf(w1, cur.x, fmaf(w2, cur.y, fmaf(w3, cur.z, bb))));
    float o3 = fmaf(w0, cur.x, fmaf(w1, cur.y, fmaf(w2, cur.z, fmaf(w3, cur.w, bb))));
    float4 o = make_float4(silu_f(o0), silu_f(o1), silu_f(o2), silu_f(o3));
    *(float4*)(xc + ((size_t)b * DI + d) * LSEQ + l0) = o;
}

// ---------------------------------------------------------------------------
// K3a: x_dbl partials.  grid (16, 4 d-parts x 2 j-groups, BN) -> 512 blocks.
// ---------------------------------------------------------------------------
__global__ __launch_bounds__(256) void k_xdbl(const float* __restrict__ xc,
                                              const float* __restrict__ xpw,
                                              float* __restrict__ xdp) {
    __shared__ float wt[22 * 96];
    const int part = blockIdx.y & 3, jg = blockIdx.y >> 2, b = blockIdx.z;
    const int l = blockIdx.x * 256 + threadIdx.x;
    const int d0 = part * 96;
    const int j0 = jg * 22;
    for (int i = threadIdx.x; i < 22 * 96; i += 256) {
        int j = i / 96, dd = i % 96;
        wt[i] = xpw[(size_t)(j0 + j) * DI + d0 + dd];
    }
    __syncthreads();
    float acc[22];
#pragma unroll
    for (int j = 0; j < 22; ++j) acc[j] = 0.f;
    const float* xcb = xc + ((size_t)b * DI + d0) * LSEQ + l;
    for (int dd = 0; dd < 96; dd += 4) {
        float v0 = xcb[(size_t)dd * LSEQ];
        float v1 = xcb[(size_t)(dd + 1) * LSEQ];
        float v2 = xcb[(size_t)(dd + 2) * LSEQ];
        float v3 = xcb[(size_t)(dd + 3) * LSEQ];
#pragma unroll
        for (int j = 0; j < 22; ++j) {
            float4 wv = *(const float4*)&wt[j * 96 + dd];
            acc[j] = fmaf(wv.x, v0, fmaf(wv.y, v1, fmaf(wv.z, v2, fmaf(wv.w, v3, acc[j]))));
        }
    }
    float* dst = xdp + (size_t)(part * BN + b) * NJ * LSEQ + (size_t)j0 * LSEQ + l;
#pragma unroll
    for (int j = 0; j < 22; ++j) dst[(size_t)j * LSEQ] = acc[j];
}

// ---------------------------------------------------------------------------
// K3c: reduce partials; route rows to dtr / B_t / C_t  ((b,n,L) layouts).
// ---------------------------------------------------------------------------
__global__ __launch_bounds__(256) void k_xdbl_reduce(const float* __restrict__ xdp,
                                                     float* __restrict__ dtr,
                                                     float* __restrict__ Bm,
                                                     float* __restrict__ Cm) {
    const int j = blockIdx.y, b = blockIdx.z;
    const int l = blockIdx.x * 256 + threadIdx.x;
    float s = 0.f;
#pragma unroll
    for (int p = 0; p < 4; ++p)
        s += xdp[(size_t)(p * BN + b) * NJ * LSEQ + (size_t)j * LSEQ + l];
    if (j < DTRK)            dtr[((size_t)b * DTRK + j) * LSEQ + l] = s;
    else if (j < DTRK + DS)  Bm[((size_t)b * DS + (j - DTRK)) * LSEQ + l] = s;
    else                     Cm[((size_t)b * DS + (j - DTRK - DS)) * LSEQ + l] = s;
}

// ---------------------------------------------------------------------------
// K3b: dt = softplus(dt_r @ dtw^T + dtb)
// ---------------------------------------------------------------------------
__global__ __launch_bounds__(256) void k_dt(const float* __restrict__ dtr,
                                            const float* __restrict__ dtw,
                                            const float* __restrict__ dtb,
                                            float* __restrict__ dt) {
    __shared__ float wt[16 * DTRK];
    __shared__ float bt[16];
    const int e0 = blockIdx.y * 16, b = blockIdx.z;
    const int l = blockIdx.x * 256 + threadIdx.x;
    if (threadIdx.x < 16 * DTRK)
        wt[threadIdx.x] = dtw[(size_t)(e0 + threadIdx.x / DTRK) * DTRK + threadIdx.x % DTRK];
    if (threadIdx.x < 16) bt[threadIdx.x] = dtb[e0 + threadIdx.x];
    __syncthreads();
    float acc[16];
#pragma unroll
    for (int e = 0; e < 16; ++e) acc[e] = 0.f;
    const float* rb = dtr + (size_t)b * DTRK * LSEQ + l;
#pragma unroll
    for (int r = 0; r < DTRK; ++r) {
        float v = rb[(size_t)r * LSEQ];
#pragma unroll
        for (int e = 0; e < 16; ++e) acc[e] = fmaf(wt[e * DTRK + r], v, acc[e]);
    }
    float* dst = dt + ((size_t)b * DI + e0) * LSEQ + l;
#pragma unroll
    for (int e = 0; e < 16; ++e) dst[(size_t)e * LSEQ] = softplus_f(acc[e] + bt[e]);
}

// ---------------------------------------------------------------------------
// K4a: scan pass 1 — per-segment (P,H) aggregates, n-outer, shuffle scan.
// ---------------------------------------------------------------------------
__global__ __launch_bounds__(256) void k_scan1(const float* __restrict__ dt,
                                               const float* __restrict__ xc,
                                               const float* __restrict__ Bm,
                                               const float* __restrict__ A_log,
                                               float* __restrict__ ws2) {
    const int lane = threadIdx.x & 63;
    const int s = blockIdx.x * 4 + (threadIdx.x >> 6);
    const int d = blockIdx.y, b = blockIdx.z;
    const int bd = b * DI + d;
    const size_t rowoff = ((size_t)b * DI + d) * LSEQ + s * SEG;
    const int l0 = lane * CHK;
    float4 da = *(const float4*)(dt + rowoff + l0);
    float4 db = *(const float4*)(dt + rowoff + l0 + 4);
    float4 xa = *(const float4*)(xc + rowoff + l0);
    float4 xb = *(const float4*)(xc + rowoff + l0 + 4);
    float dt8[8] = {da.x, da.y, da.z, da.w, db.x, db.y, db.z, db.w};
    float dx8[8] = {da.x * xa.x, da.y * xa.y, da.z * xa.z, da.w * xa.w,
                    db.x * xb.x, db.y * xb.y, db.z * xb.z, db.w * xb.w};
    const float* Alogd = A_log + (size_t)d * DS;
    float* wout = ws2 + (size_t)(bd * NSPLIT + s) * 32;

    for (int n = 0; n < DS; ++n) {
        const float An = -__expf(Alogd[n]);
        const float* Bn = Bm + ((size_t)(b * DS + n)) * LSEQ + s * SEG + l0;
        float4 Ba = *(const float4*)Bn;
        float4 Bb = *(const float4*)(Bn + 4);
        float B8[8] = {Ba.x, Ba.y, Ba.z, Ba.w, Bb.x, Bb.y, Bb.z, Bb.w};
        float p = 1.f, h = 0.f;
#pragma unroll
        for (int i = 0; i < CHK; ++i) {
            float dA = __expf(dt8[i] * An);
            h = fmaf(dA, h, dx8[i] * B8[i]);
            p *= dA;
        }
        wave_scan_ph(p, h, lane);
        if (lane == 63) { wout[n] = p; wout[16 + n] = h; }
    }
}

// ---------------------------------------------------------------------------
// K4b: scan the 8 segment aggregates per (b,d,n) → exclusive carry-in ws3.
// ---------------------------------------------------------------------------
__global__ __launch_bounds__(256) void k_scan2(const float* __restrict__ ws2,
                                               float* __restrict__ ws3) {
    const int t = blockIdx.x * 256 + threadIdx.x;   // (bd)*16 + n
    const int n = t & 15;
    const int bd = t >> 4;
    float hc = 0.f;
#pragma unroll
    for (int s = 0; s < NSPLIT; ++s) {
        const float* w = ws2 + (size_t)(bd * NSPLIT + s) * 32;
        float P = w[n], H = w[16 + n];
        ws3[(size_t)(bd * NSPLIT + s) * DS + n] = hc;
        hc = fmaf(P, hc, H);
    }
}

// ---------------------------------------------------------------------------
// K4c: scan pass 3 — n-outer, shuffle scan, replay accumulating y, gate.
// ---------------------------------------------------------------------------
__global__ __launch_bounds__(256) void k_scan3(const float* __restrict__ dt,
                                               const float* __restrict__ xc,
                                               const float* __restrict__ Bm,
                                               const float* __restrict__ Cm,
                                               const float* __restrict__ zs,
                                               const float* __restrict__ A_log,
                                               const float* __restrict__ Dp,
                                               const float* __restrict__ ws3,
                                               float* __restrict__ g) {
    const int lane = threadIdx.x & 63;
    const int s = blockIdx.x * 4 + (threadIdx.x >> 6);
    const int d = blockIdx.y, b = blockIdx.z;
    const int bd = b * DI + d;
    const size_t rowoff = ((size_t)b * DI + d) * LSEQ + s * SEG;
    const int l0 = lane * CHK;
    float4 da = *(const float4*)(dt + rowoff + l0);
    float4 db = *(const float4*)(dt + rowoff + l0 + 4);
    float4 xa = *(const float4*)(xc + rowoff + l0);
    float4 xb = *(const float4*)(xc + rowoff + l0 + 4);
    float4 za = *(const float4*)(zs + rowoff + l0);
    float4 zb = *(const float4*)(zs + rowoff + l0 + 4);
    float dt8[8] = {da.x, da.y, da.z, da.w, db.x, db.y, db.z, db.w};
    float xc8[8] = {xa.x, xa.y, xa.z, xa.w, xb.x, xb.y, xb.z, xb.w};
    float z8[8]  = {za.x, za.y, za.z, za.w, zb.x, zb.y, zb.z, zb.w};
    float dx8[8];
#pragma unroll
    for (int i = 0; i < CHK; ++i) dx8[i] = dt8[i] * xc8[i];
    float y8[8] = {0.f, 0.f, 0.f, 0.f, 0.f, 0.f, 0.f, 0.f};
    const float* Alogd = A_log + (size_t)d * DS;
    const float* carry = ws3 + (size_t)(bd * NSPLIT + s) * DS;

    for (int n = 0; n < DS; ++n) {
        const float An = -__expf(Alogd[n]);
        const size_t nloff = ((size_t)(b * DS + n)) * LSEQ + s * SEG + l0;
        float4 Ba = *(const float4*)(Bm + nloff);
        float4 Bb = *(const float4*)(Bm + nloff + 4);
        float4 Ca = *(const float4*)(Cm + nloff);
        float4 Cb = *(const float4*)(Cm + nloff + 4);
        float B8[8] = {Ba.x, Ba.y, Ba.z, Ba.w, Bb.x, Bb.y, Bb.z, Bb.w};
        float C8[8] = {Ca.x, Ca.y, Ca.z, Ca.w, Cb.x, Cb.y, Cb.z, Cb.w};
        float dA8[8];
        float p = 1.f, h = 0.f;
#pragma unroll
        for (int i = 0; i < CHK; ++i) {
            float dA = __expf(dt8[i] * An);
            dA8[i] = dA;
            h = fmaf(dA, h, dx8[i] * B8[i]);
            p *= dA;
        }
        wave_scan_ph(p, h, lane);
        float Pe = __shfl_up(p, 1u);
        float He = __shfl_up(h, 1u);
        if (lane == 0) { Pe = 1.f; He = 0.f; }
        float hv = fmaf(Pe, carry[n], He);   // h entering this lane's chunk
#pragma unroll
        for (int i = 0; i < CHK; ++i) {
            hv = fmaf(dA8[i], hv, dx8[i] * B8[i]);
            y8[i] = fmaf(hv, C8[i], y8[i]);
        }
    }
    const float Dd = Dp[d];
    float out8[8];
#pragma unroll
    for (int i = 0; i < CHK; ++i) out8[i] = fmaf(Dd, xc8[i], y8[i]) * z8[i];
    float* grow = g + rowoff;
    *(float4*)(grow + l0)     = make_float4(out8[0], out8[1], out8[2], out8[3]);
    *(float4*)(grow + l0 + 4) = make_float4(out8[4], out8[5], out8[6], out8[7]);
}

// ---------------------------------------------------------------------------
// K5: out_proj.  grid (8, 24, BN), 2 l per thread, 8 c per block.
// ---------------------------------------------------------------------------
__global__ __launch_bounds__(256) void k_outproj(const float* __restrict__ g,
                                                 const float* __restrict__ wout,
                                                 float* __restrict__ out) {
    __shared__ float wt[8 * DI];
    const int c0 = blockIdx.y * 8, b = blockIdx.z;
    const int l0 = blockIdx.x * 512 + threadIdx.x * 2;
    for (int i = threadIdx.x; i < 8 * DI; i += 256)
        wt[i] = wout[(size_t)(c0 + i / DI) * DI + i % DI];
    __syncthreads();
    float acc[8][2];
#pragma unroll
    for (int cc = 0; cc < 8; ++cc) { acc[cc][0] = acc[cc][1] = 0.f; }
    const float* gb = g + (size_t)b * DI * LSEQ + l0;
    for (int d = 0; d < DI; d += 4) {
        float2 g0 = *(const float2*)(gb + (size_t)d * LSEQ);
        float2 g1 = *(const float2*)(gb + (size_t)(d + 1) * LSEQ);
        float2 g2 = *(const float2*)(gb + (size_t)(d + 2) * LSEQ);
        float2 g3 = *(const float2*)(gb + (size_t)(d + 3) * LSEQ);
#pragma unroll
        for (int cc = 0; cc < 8; ++cc) {
            float4 wv = *(const float4*)&wt[cc * DI + d];
            acc[cc][0] = fmaf(wv.x, g0.x, fmaf(wv.y, g1.x, fmaf(wv.z, g2.x, fmaf(wv.w, g3.x, acc[cc][0]))));
            acc[cc][1] = fmaf(wv.x, g0.y, fmaf(wv.y, g1.y, fmaf(wv.z, g2.y, fmaf(wv.w, g3.y, acc[cc][1]))));
        }
    }
#pragma unroll
    for (int cc = 0; cc < 8; ++cc) {
        float2 v = make_float2(acc[cc][0], acc[cc][1]);
        *(float2*)(out + ((size_t)b * CD + c0 + cc) * LSEQ + l0) = v;
    }
}

extern "C" void kernel_launch(void* const* d_in, const int* in_sizes, int n_in,
                              void* d_out, int out_size, void* d_ws, size_t ws_size,
                              hipStream_t stream) {
    const float* x     = (const float*)d_in[0];
    const float* w_in  = (const float*)d_in[1];
    const float* cw    = (const float*)d_in[2];
    const float* cb    = (const float*)d_in[3];
    const float* xpw   = (const float*)d_in[4];
    const float* dtw   = (const float*)d_in[5];
    const float* dtbv  = (const float*)d_in[6];
    const float* A_log = (const float*)d_in[7];
    const float* Dp    = (const float*)d_in[8];
    const float* wout  = (const float*)d_in[9];
    float* out = (float*)d_out;

    float* ws = (float*)d_ws;
    const size_t NBL = (size_t)BN * DI * LSEQ;            // 6,291,456 floats
    float* xp  = ws;                                      // (b,384,L)
    float* zs  = xp + NBL;                                // silu(z)
    float* xc  = zs + NBL;                                // conv out
    float* dt  = xc + NBL;                                // softplus dt
    float* Bm  = dt + NBL;                                // (b,16,L) transposed
    float* Cm  = Bm + (size_t)BN * LSEQ * DS;             // (b,16,L) transposed
    float* dtr = Cm + (size_t)BN * LSEQ * DS;             // (b,12,L)
    float* xdp = dtr + (size_t)BN * DTRK * LSEQ;          // 4 x (b,44,L); dead after k_dt
    float* g   = xp;                                      // reuse xp after conv
    float* ws2 = xdp;                                     // 12288 * 32 floats
    float* ws3 = ws2 + (size_t)BN * DI * NSPLIT * 32;     // 12288 * 16 floats

    k_inproj     <<<dim3(8, 48, BN), 256, 0, stream>>>(x, w_in, xp, zs);
    k_conv       <<<dim3(4, DI, BN), 256, 0, stream>>>(xp, cw, cb, xc);
    k_xdbl       <<<dim3(16, 8, BN), 256, 0, stream>>>(xc, xpw, xdp);
    k_xdbl_reduce<<<dim3(16, NJ, BN), 256, 0, stream>>>(xdp, dtr, Bm, Cm);
    k_dt         <<<dim3(16, 24, BN), 256, 0, stream>>>(dtr, dtw, dtbv, dt);
    k_scan1      <<<dim3(NSPLIT / 4, DI, BN), 256, 0, stream>>>(dt, xc, Bm, A_log, ws2);
    k_scan2      <<<dim3(96), 256, 0, stream>>>(ws2, ws3);
    k_scan3      <<<dim3(NSPLIT / 4, DI, BN), 256, 0, stream>>>(dt, xc, Bm, Cm, zs, A_log, Dp, ws3, g);
    k_outproj    <<<dim3(8, 24, BN), 256, 0, stream>>>(g, wout, out);
}

// Round 5
// 328.081 us; speedup vs baseline: 2.0375x; 1.0691x over previous
//
#include <hip/hip_runtime.h>
#include <math.h>

#define BN   4
#define CD   192
#define LSEQ 4096
#define DI   384
#define DTRK 12
#define DS   16
#define NJ   44
#define NSPLIT 8          // L-segments per (b,d) row
#define SEG  512          // LSEQ / NSPLIT
#define CHK  8            // steps per thread (SEG / 64)

__device__ __forceinline__ float silu_f(float x) { return x / (1.f + __expf(-x)); }
__device__ __forceinline__ float softplus_f(float x) {
    return (x > 15.f) ? x : log1pf(__expf(x));
}

// Inclusive Hillis-Steele scan of affine elements (P,H) across the 64-lane wave.
__device__ __forceinline__ void wave_scan_ph(float& P, float& H, int lane) {
#pragma unroll
    for (int delta = 1; delta < 64; delta <<= 1) {
        float Pp = __shfl_up(P, (unsigned)delta);
        float Hp = __shfl_up(H, (unsigned)delta);
        bool v = (lane >= delta);
        Pp = v ? Pp : 1.0f;
        Hp = v ? Hp : 0.0f;
        H = fmaf(P, Hp, H);   // uses pre-update P
        P *= Pp;
    }
}

// ---------------------------------------------------------------------------
// K1: in_proj.  grid (4, 48, BN), 4 l/thread (float4), 16 e rows per block.
// Weights read as wave-uniform scalars (s_load -> SGPR operand of v_fma);
// no LDS, no barriers -> compiler pipelines the x loads.
// ---------------------------------------------------------------------------
__global__ __launch_bounds__(256) void k_inproj(const float* __restrict__ x,
                                                const float* __restrict__ w,
                                                float* __restrict__ xp,
                                                float* __restrict__ zs) {
    const int b  = blockIdx.z;
    const int e0 = blockIdx.y * 16;
    const int l0 = blockIdx.x * 1024 + threadIdx.x * 4;
    float4 acc[16];
#pragma unroll
    for (int e = 0; e < 16; ++e) acc[e] = make_float4(0.f, 0.f, 0.f, 0.f);
    const float* xb = x + (size_t)b * CD * LSEQ + l0;
    const float* wb = w + (size_t)e0 * CD;
    for (int c = 0; c < CD; c += 4) {
        float4 x0 = *(const float4*)(xb + (size_t)c * LSEQ);
        float4 x1 = *(const float4*)(xb + (size_t)(c + 1) * LSEQ);
        float4 x2 = *(const float4*)(xb + (size_t)(c + 2) * LSEQ);
        float4 x3 = *(const float4*)(xb + (size_t)(c + 3) * LSEQ);
#pragma unroll
        for (int e = 0; e < 16; ++e) {
            const float* we = wb + (size_t)e * CD + c;   // uniform -> SGPR
            float w0 = we[0], w1 = we[1], w2 = we[2], w3 = we[3];
            acc[e].x = fmaf(w0, x0.x, fmaf(w1, x1.x, fmaf(w2, x2.x, fmaf(w3, x3.x, acc[e].x))));
            acc[e].y = fmaf(w0, x0.y, fmaf(w1, x1.y, fmaf(w2, x2.y, fmaf(w3, x3.y, acc[e].y))));
            acc[e].z = fmaf(w0, x0.z, fmaf(w1, x1.z, fmaf(w2, x2.z, fmaf(w3, x3.z, acc[e].z))));
            acc[e].w = fmaf(w0, x0.w, fmaf(w1, x1.w, fmaf(w2, x2.w, fmaf(w3, x3.w, acc[e].w))));
        }
    }
    const bool is_z = (e0 >= DI);
#pragma unroll
    for (int e = 0; e < 16; ++e) {
        float4 v = acc[e];
        if (is_z) { v.x = silu_f(v.x); v.y = silu_f(v.y); v.z = silu_f(v.z); v.w = silu_f(v.w); }
        int row = is_z ? (e0 - DI + e) : (e0 + e);
        float* dst = (is_z ? zs : xp) + ((size_t)b * DI + row) * LSEQ + l0;
        *(float4*)dst = v;
    }
}

// ---------------------------------------------------------------------------
// K2: depthwise causal conv(4) + bias + silu.
// ---------------------------------------------------------------------------
__global__ __launch_bounds__(256) void k_conv(const float* __restrict__ xp,
                                              const float* __restrict__ cw,
                                              const float* __restrict__ cb,
                                              float* __restrict__ xc) {
    const int d = blockIdx.y, b = blockIdx.z;
    const int l0 = blockIdx.x * 1024 + threadIdx.x * 4;
    const float w0 = cw[d * 4 + 0], w1 = cw[d * 4 + 1], w2 = cw[d * 4 + 2], w3 = cw[d * 4 + 3];
    const float bb = cb[d];
    const float* row = xp + ((size_t)b * DI + d) * LSEQ;
    float4 cur = *(const float4*)(row + l0);
    float4 pv;
    if (l0 == 0) pv = make_float4(0.f, 0.f, 0.f, 0.f);
    else         pv = *(const float4*)(row + l0 - 4);
    float o0 = fmaf(w0, pv.y, fmaf(w1, pv.z, fmaf(w2, pv.w, fmaf(w3, cur.x, bb))));
    float o1 = fmaf(w0, pv.z, fmaf(w1, pv.w, fmaf(w2, cur.x, fmaf(w3, cur.y, bb))));
    float o2 = fmaf(w0, pv.w, fmaf(w1, cur.x, fmaf(w2, cur.y, fmaf(w3, cur.z, bb))));
    float o3 = fmaf(w0, cur.x, fmaf(w1, cur.y, fmaf(w2, cur.z, fmaf(w3, cur.w, bb))));
    float4 o = make_float4(silu_f(o0), silu_f(o1), silu_f(o2), silu_f(o3));
    *(float4*)(xc + ((size_t)b * DI + d) * LSEQ + l0) = o;
}

// ---------------------------------------------------------------------------
// K3a: x_dbl partials.  grid (16, 4 d-parts x 2 j-groups, BN); scalar weights.
// ---------------------------------------------------------------------------
__global__ __launch_bounds__(256) void k_xdbl(const float* __restrict__ xc,
                                              const float* __restrict__ xpw,
                                              float* __restrict__ xdp) {
    const int part = blockIdx.y & 3, jg = blockIdx.y >> 2, b = blockIdx.z;
    const int l = blockIdx.x * 256 + threadIdx.x;
    const int d0 = part * 96;
    const int j0 = jg * 22;
    float acc[22];
#pragma unroll
    for (int j = 0; j < 22; ++j) acc[j] = 0.f;
    const float* xcb = xc + ((size_t)b * DI + d0) * LSEQ + l;
    const float* wb  = xpw + (size_t)j0 * DI + d0;
    for (int dd = 0; dd < 96; dd += 4) {
        float v0 = xcb[(size_t)dd * LSEQ];
        float v1 = xcb[(size_t)(dd + 1) * LSEQ];
        float v2 = xcb[(size_t)(dd + 2) * LSEQ];
        float v3 = xcb[(size_t)(dd + 3) * LSEQ];
#pragma unroll
        for (int j = 0; j < 22; ++j) {
            const float* wj = wb + (size_t)j * DI + dd;   // uniform -> SGPR
            acc[j] = fmaf(wj[0], v0, fmaf(wj[1], v1, fmaf(wj[2], v2, fmaf(wj[3], v3, acc[j]))));
        }
    }
    float* dst = xdp + (size_t)(part * BN + b) * NJ * LSEQ + (size_t)j0 * LSEQ + l;
#pragma unroll
    for (int j = 0; j < 22; ++j) dst[(size_t)j * LSEQ] = acc[j];
}

// ---------------------------------------------------------------------------
// K3c: reduce partials; route rows to dtr / B_t / C_t  ((b,n,L) layouts).
// ---------------------------------------------------------------------------
__global__ __launch_bounds__(256) void k_xdbl_reduce(const float* __restrict__ xdp,
                                                     float* __restrict__ dtr,
                                                     float* __restrict__ Bm,
                                                     float* __restrict__ Cm) {
    const int j = blockIdx.y, b = blockIdx.z;
    const int l = blockIdx.x * 256 + threadIdx.x;
    float s = 0.f;
#pragma unroll
    for (int p = 0; p < 4; ++p)
        s += xdp[(size_t)(p * BN + b) * NJ * LSEQ + (size_t)j * LSEQ + l];
    if (j < DTRK)            dtr[((size_t)b * DTRK + j) * LSEQ + l] = s;
    else if (j < DTRK + DS)  Bm[((size_t)b * DS + (j - DTRK)) * LSEQ + l] = s;
    else                     Cm[((size_t)b * DS + (j - DTRK - DS)) * LSEQ + l] = s;
}

// ---------------------------------------------------------------------------
// K3b: dt = softplus(dt_r @ dtw^T + dtb); scalar weights, no LDS.
// ---------------------------------------------------------------------------
__global__ __launch_bounds__(256) void k_dt(const float* __restrict__ dtr,
                                            const float* __restrict__ dtw,
                                            const float* __restrict__ dtb,
                                            float* __restrict__ dt) {
    const int e0 = blockIdx.y * 16, b = blockIdx.z;
    const int l = blockIdx.x * 256 + threadIdx.x;
    float acc[16];
#pragma unroll
    for (int e = 0; e < 16; ++e) acc[e] = 0.f;
    const float* rb = dtr + (size_t)b * DTRK * LSEQ + l;
#pragma unroll
    for (int r = 0; r < DTRK; ++r) {
        float v = rb[(size_t)r * LSEQ];
#pragma unroll
        for (int e = 0; e < 16; ++e)
            acc[e] = fmaf(dtw[(size_t)(e0 + e) * DTRK + r], v, acc[e]);   // uniform
    }
    float* dst = dt + ((size_t)b * DI + e0) * LSEQ + l;
#pragma unroll
    for (int e = 0; e < 16; ++e) dst[(size_t)e * LSEQ] = softplus_f(acc[e] + dtb[e0 + e]);
}

// ---------------------------------------------------------------------------
// K4a: scan pass 1 — per-segment (P,H) aggregates, n-outer, shuffle scan.
// ---------------------------------------------------------------------------
__global__ __launch_bounds__(256) void k_scan1(const float* __restrict__ dt,
                                               const float* __restrict__ xc,
                                               const float* __restrict__ Bm,
                                               const float* __restrict__ A_log,
                                               float* __restrict__ ws2) {
    const int lane = threadIdx.x & 63;
    const int s = blockIdx.x * 4 + (threadIdx.x >> 6);
    const int d = blockIdx.y, b = blockIdx.z;
    const int bd = b * DI + d;
    const size_t rowoff = ((size_t)b * DI + d) * LSEQ + s * SEG;
    const int l0 = lane * CHK;
    float4 da = *(const float4*)(dt + rowoff + l0);
    float4 db = *(const float4*)(dt + rowoff + l0 + 4);
    float4 xa = *(const float4*)(xc + rowoff + l0);
    float4 xb = *(const float4*)(xc + rowoff + l0 + 4);
    float dt8[8] = {da.x, da.y, da.z, da.w, db.x, db.y, db.z, db.w};
    float dx8[8] = {da.x * xa.x, da.y * xa.y, da.z * xa.z, da.w * xa.w,
                    db.x * xb.x, db.y * xb.y, db.z * xb.z, db.w * xb.w};
    const float* Alogd = A_log + (size_t)d * DS;
    float* wout = ws2 + (size_t)(bd * NSPLIT + s) * 32;

    for (int n = 0; n < DS; ++n) {
        const float An = -__expf(Alogd[n]);
        const float* Bn = Bm + ((size_t)(b * DS + n)) * LSEQ + s * SEG + l0;
        float4 Ba = *(const float4*)Bn;
        float4 Bb = *(const float4*)(Bn + 4);
        float B8[8] = {Ba.x, Ba.y, Ba.z, Ba.w, Bb.x, Bb.y, Bb.z, Bb.w};
        float p = 1.f, h = 0.f;
#pragma unroll
        for (int i = 0; i < CHK; ++i) {
            float dA = __expf(dt8[i] * An);
            h = fmaf(dA, h, dx8[i] * B8[i]);
            p *= dA;
        }
        wave_scan_ph(p, h, lane);
        if (lane == 63) { wout[n] = p; wout[16 + n] = h; }
    }
}

// ---------------------------------------------------------------------------
// K4b: scan the 8 segment aggregates per (b,d,n) → exclusive carry-in ws3.
// ---------------------------------------------------------------------------
__global__ __launch_bounds__(256) void k_scan2(const float* __restrict__ ws2,
                                               float* __restrict__ ws3) {
    const int t = blockIdx.x * 256 + threadIdx.x;   // (bd)*16 + n
    const int n = t & 15;
    const int bd = t >> 4;
    float hc = 0.f;
#pragma unroll
    for (int s = 0; s < NSPLIT; ++s) {
        const float* w = ws2 + (size_t)(bd * NSPLIT + s) * 32;
        float P = w[n], H = w[16 + n];
        ws3[(size_t)(bd * NSPLIT + s) * DS + n] = hc;
        hc = fmaf(P, hc, H);
    }
}

// ---------------------------------------------------------------------------
// K4c: scan pass 3 — n-outer, shuffle scan, replay accumulating y, gate.
// ---------------------------------------------------------------------------
__global__ __launch_bounds__(256) void k_scan3(const float* __restrict__ dt,
                                               const float* __restrict__ xc,
                                               const float* __restrict__ Bm,
                                               const float* __restrict__ Cm,
                                               const float* __restrict__ zs,
                                               const float* __restrict__ A_log,
                                               const float* __restrict__ Dp,
                                               const float* __restrict__ ws3,
                                               float* __restrict__ g) {
    const int lane = threadIdx.x & 63;
    const int s = blockIdx.x * 4 + (threadIdx.x >> 6);
    const int d = blockIdx.y, b = blockIdx.z;
    const int bd = b * DI + d;
    const size_t rowoff = ((size_t)b * DI + d) * LSEQ + s * SEG;
    const int l0 = lane * CHK;
    float4 da = *(const float4*)(dt + rowoff + l0);
    float4 db = *(const float4*)(dt + rowoff + l0 + 4);
    float4 xa = *(const float4*)(xc + rowoff + l0);
    float4 xb = *(const float4*)(xc + rowoff + l0 + 4);
    float4 za = *(const float4*)(zs + rowoff + l0);
    float4 zb = *(const float4*)(zs + rowoff + l0 + 4);
    float dt8[8] = {da.x, da.y, da.z, da.w, db.x, db.y, db.z, db.w};
    float xc8[8] = {xa.x, xa.y, xa.z, xa.w, xb.x, xb.y, xb.z, xb.w};
    float z8[8]  = {za.x, za.y, za.z, za.w, zb.x, zb.y, zb.z, zb.w};
    float dx8[8];
#pragma unroll
    for (int i = 0; i < CHK; ++i) dx8[i] = dt8[i] * xc8[i];
    float y8[8] = {0.f, 0.f, 0.f, 0.f, 0.f, 0.f, 0.f, 0.f};
    const float* Alogd = A_log + (size_t)d * DS;
    const float* carry = ws3 + (size_t)(bd * NSPLIT + s) * DS;

    for (int n = 0; n < DS; ++n) {
        const float An = -__expf(Alogd[n]);
        const size_t nloff = ((size_t)(b * DS + n)) * LSEQ + s * SEG + l0;
        float4 Ba = *(const float4*)(Bm + nloff);
        float4 Bb = *(const float4*)(Bm + nloff + 4);
        float4 Ca = *(const float4*)(Cm + nloff);
        float4 Cb = *(const float4*)(Cm + nloff + 4);
        float B8[8] = {Ba.x, Ba.y, Ba.z, Ba.w, Bb.x, Bb.y, Bb.z, Bb.w};
        float C8[8] = {Ca.x, Ca.y, Ca.z, Ca.w, Cb.x, Cb.y, Cb.z, Cb.w};
        float dA8[8];
        float p = 1.f, h = 0.f;
#pragma unroll
        for (int i = 0; i < CHK; ++i) {
            float dA = __expf(dt8[i] * An);
            dA8[i] = dA;
            h = fmaf(dA, h, dx8[i] * B8[i]);
            p *= dA;
        }
        wave_scan_ph(p, h, lane);
        float Pe = __shfl_up(p, 1u);
        float He = __shfl_up(h, 1u);
        if (lane == 0) { Pe = 1.f; He = 0.f; }
        float hv = fmaf(Pe, carry[n], He);   // h entering this lane's chunk
#pragma unroll
        for (int i = 0; i < CHK; ++i) {
            hv = fmaf(dA8[i], hv, dx8[i] * B8[i]);
            y8[i] = fmaf(hv, C8[i], y8[i]);
        }
    }
    const float Dd = Dp[d];
    float out8[8];
#pragma unroll
    for (int i = 0; i < CHK; ++i) out8[i] = fmaf(Dd, xc8[i], y8[i]) * z8[i];
    float* grow = g + rowoff;
    *(float4*)(grow + l0)     = make_float4(out8[0], out8[1], out8[2], out8[3]);
    *(float4*)(grow + l0 + 4) = make_float4(out8[4], out8[5], out8[6], out8[7]);
}

// ---------------------------------------------------------------------------
// K5: out_proj.  grid (8, 24, BN), 2 l/thread, 8 c per block; scalar weights.
// ---------------------------------------------------------------------------
__global__ __launch_bounds__(256) void k_outproj(const float* __restrict__ g,
                                                 const float* __restrict__ wout,
                                                 float* __restrict__ out) {
    const int c0 = blockIdx.y * 8, b = blockIdx.z;
    const int l0 = blockIdx.x * 512 + threadIdx.x * 2;
    float2 acc[8];
#pragma unroll
    for (int cc = 0; cc < 8; ++cc) acc[cc] = make_float2(0.f, 0.f);
    const float* gb = g + (size_t)b * DI * LSEQ + l0;
    const float* wb = wout + (size_t)c0 * DI;
    for (int d = 0; d < DI; d += 4) {
        float2 g0 = *(const float2*)(gb + (size_t)d * LSEQ);
        float2 g1 = *(const float2*)(gb + (size_t)(d + 1) * LSEQ);
        float2 g2 = *(const float2*)(gb + (size_t)(d + 2) * LSEQ);
        float2 g3 = *(const float2*)(gb + (size_t)(d + 3) * LSEQ);
#pragma unroll
        for (int cc = 0; cc < 8; ++cc) {
            const float* wc = wb + (size_t)cc * DI + d;   // uniform -> SGPR
            float w0 = wc[0], w1 = wc[1], w2 = wc[2], w3 = wc[3];
            acc[cc].x = fmaf(w0, g0.x, fmaf(w1, g1.x, fmaf(w2, g2.x, fmaf(w3, g3.x, acc[cc].x))));
            acc[cc].y = fmaf(w0, g0.y, fmaf(w1, g1.y, fmaf(w2, g2.y, fmaf(w3, g3.y, acc[cc].y))));
        }
    }
#pragma unroll
    for (int cc = 0; cc < 8; ++cc)
        *(float2*)(out + ((size_t)b * CD + c0 + cc) * LSEQ + l0) = acc[cc];
}

extern "C" void kernel_launch(void* const* d_in, const int* in_sizes, int n_in,
                              void* d_out, int out_size, void* d_ws, size_t ws_size,
                              hipStream_t stream) {
    const float* x     = (const float*)d_in[0];
    const float* w_in  = (const float*)d_in[1];
    const float* cw    = (const float*)d_in[2];
    const float* cb    = (const float*)d_in[3];
    const float* xpw   = (const float*)d_in[4];
    const float* dtw   = (const float*)d_in[5];
    const float* dtbv  = (const float*)d_in[6];
    const float* A_log = (const float*)d_in[7];
    const float* Dp    = (const float*)d_in[8];
    const float* wout  = (const float*)d_in[9];
    float* out = (float*)d_out;

    float* ws = (float*)d_ws;
    const size_t NBL = (size_t)BN * DI * LSEQ;            // 6,291,456 floats
    float* xp  = ws;                                      // (b,384,L)
    float* zs  = xp + NBL;                                // silu(z)
    float* xc  = zs + NBL;                                // conv out
    float* dt  = xc + NBL;                                // softplus dt
    float* Bm  = dt + NBL;                                // (b,16,L) transposed
    float* Cm  = Bm + (size_t)BN * LSEQ * DS;             // (b,16,L) transposed
    float* dtr = Cm + (size_t)BN * LSEQ * DS;             // (b,12,L)
    float* xdp = dtr + (size_t)BN * DTRK * LSEQ;          // 4 x (b,44,L); dead after k_dt
    float* g   = xp;                                      // reuse xp after conv
    float* ws2 = xdp;                                     // 12288 * 32 floats
    float* ws3 = ws2 + (size_t)BN * DI * NSPLIT * 32;     // 12288 * 16 floats

    k_inproj     <<<dim3(4, 48, BN), 256, 0, stream>>>(x, w_in, xp, zs);
    k_conv       <<<dim3(4, DI, BN), 256, 0, stream>>>(xp, cw, cb, xc);
    k_xdbl       <<<dim3(16, 8, BN), 256, 0, stream>>>(xc, xpw, xdp);
    k_xdbl_reduce<<<dim3(16, NJ, BN), 256, 0, stream>>>(xdp, dtr, Bm, Cm);
    k_dt         <<<dim3(16, 24, BN), 256, 0, stream>>>(dtr, dtw, dtbv, dt);
    k_scan1      <<<dim3(NSPLIT / 4, DI, BN), 256, 0, stream>>>(dt, xc, Bm, A_log, ws2);
    k_scan2      <<<dim3(96), 256, 0, stream>>>(ws2, ws3);
    k_scan3      <<<dim3(NSPLIT / 4, DI, BN), 256, 0, stream>>>(dt, xc, Bm, Cm, zs, A_log, Dp, ws3, g);
    k_outproj    <<<dim3(8, 24, BN), 256, 0, stream>>>(g, wout, out);
}

// Round 6
// 327.179 us; speedup vs baseline: 2.0432x; 1.0028x over previous
//
#include <hip/hip_runtime.h>
#include <math.h>

#define BN   4
#define CD   192
#define LSEQ 4096
#define DI   384
#define DTRK 12
#define DS   16
#define NJ   44
#define NSPLIT 8          // L-segments per (b,d) row
#define SEG  512          // LSEQ / NSPLIT
#define CHK  8            // steps per thread (SEG / 64)

__device__ __forceinline__ float silu_f(float x) { return x / (1.f + __expf(-x)); }
__device__ __forceinline__ float softplus_f(float x) {
    return (x > 15.f) ? x : log1pf(__expf(x));
}

// Inclusive Hillis-Steele scan of affine elements (P,H) across the 64-lane wave.
__device__ __forceinline__ void wave_scan_ph(float& P, float& H, int lane) {
#pragma unroll
    for (int delta = 1; delta < 64; delta <<= 1) {
        float Pp = __shfl_up(P, (unsigned)delta);
        float Hp = __shfl_up(H, (unsigned)delta);
        bool v = (lane >= delta);
        Pp = v ? Pp : 1.0f;
        Hp = v ? Hp : 0.0f;
        H = fmaf(P, Hp, H);   // uses pre-update P
        P *= Pp;
    }
}

// ---------------------------------------------------------------------------
// K1: in_proj.  grid (4, 96, BN): 8 e rows/block, 4 l/thread (float4).
// 1536 blocks = 6 blocks/CU = 24 waves/CU.  Scalar (SGPR) weights, no LDS.
// ---------------------------------------------------------------------------
__global__ __launch_bounds__(256) void k_inproj(const float* __restrict__ x,
                                                const float* __restrict__ w,
                                                float* __restrict__ xp,
                                                float* __restrict__ zs) {
    const int b  = blockIdx.z;
    const int e0 = blockIdx.y * 8;
    const int l0 = blockIdx.x * 1024 + threadIdx.x * 4;
    float4 acc[8];
#pragma unroll
    for (int e = 0; e < 8; ++e) acc[e] = make_float4(0.f, 0.f, 0.f, 0.f);
    const float* xb = x + (size_t)b * CD * LSEQ + l0;
    const float* wb = w + (size_t)e0 * CD;
    for (int c = 0; c < CD; c += 4) {
        float4 x0 = *(const float4*)(xb + (size_t)c * LSEQ);
        float4 x1 = *(const float4*)(xb + (size_t)(c + 1) * LSEQ);
        float4 x2 = *(const float4*)(xb + (size_t)(c + 2) * LSEQ);
        float4 x3 = *(const float4*)(xb + (size_t)(c + 3) * LSEQ);
#pragma unroll
        for (int e = 0; e < 8; ++e) {
            const float* we = wb + (size_t)e * CD + c;   // uniform -> SGPR
            float w0 = we[0], w1 = we[1], w2 = we[2], w3 = we[3];
            acc[e].x = fmaf(w0, x0.x, fmaf(w1, x1.x, fmaf(w2, x2.x, fmaf(w3, x3.x, acc[e].x))));
            acc[e].y = fmaf(w0, x0.y, fmaf(w1, x1.y, fmaf(w2, x2.y, fmaf(w3, x3.y, acc[e].y))));
            acc[e].z = fmaf(w0, x0.z, fmaf(w1, x1.z, fmaf(w2, x2.z, fmaf(w3, x3.z, acc[e].z))));
            acc[e].w = fmaf(w0, x0.w, fmaf(w1, x1.w, fmaf(w2, x2.w, fmaf(w3, x3.w, acc[e].w))));
        }
    }
    const bool is_z = (e0 >= DI);
#pragma unroll
    for (int e = 0; e < 8; ++e) {
        float4 v = acc[e];
        if (is_z) { v.x = silu_f(v.x); v.y = silu_f(v.y); v.z = silu_f(v.z); v.w = silu_f(v.w); }
        int row = is_z ? (e0 - DI + e) : (e0 + e);
        float* dst = (is_z ? zs : xp) + ((size_t)b * DI + row) * LSEQ + l0;
        *(float4*)dst = v;
    }
}

// ---------------------------------------------------------------------------
// K2: depthwise causal conv(4) + bias + silu.
// ---------------------------------------------------------------------------
__global__ __launch_bounds__(256) void k_conv(const float* __restrict__ xp,
                                              const float* __restrict__ cw,
                                              const float* __restrict__ cb,
                                              float* __restrict__ xc) {
    const int d = blockIdx.y, b = blockIdx.z;
    const int l0 = blockIdx.x * 1024 + threadIdx.x * 4;
    const float w0 = cw[d * 4 + 0], w1 = cw[d * 4 + 1], w2 = cw[d * 4 + 2], w3 = cw[d * 4 + 3];
    const float bb = cb[d];
    const float* row = xp + ((size_t)b * DI + d) * LSEQ;
    float4 cur = *(const float4*)(row + l0);
    float4 pv;
    if (l0 == 0) pv = make_float4(0.f, 0.f, 0.f, 0.f);
    else         pv = *(const float4*)(row + l0 - 4);
    float o0 = fmaf(w0, pv.y, fmaf(w1, pv.z, fmaf(w2, pv.w, fmaf(w3, cur.x, bb))));
    float o1 = fmaf(w0, pv.z, fmaf(w1, pv.w, fmaf(w2, cur.x, fmaf(w3, cur.y, bb))));
    float o2 = fmaf(w0, pv.w, fmaf(w1, cur.x, fmaf(w2, cur.y, fmaf(w3, cur.z, bb))));
    float o3 = fmaf(w0, cur.x, fmaf(w1, cur.y, fmaf(w2, cur.z, fmaf(w3, cur.w, bb))));
    float4 o = make_float4(silu_f(o0), silu_f(o1), silu_f(o2), silu_f(o3));
    *(float4*)(xc + ((size_t)b * DI + d) * LSEQ + l0) = o;
}

// ---------------------------------------------------------------------------
// K3a: x_dbl partials.  grid (16, 4 d-parts x 2 j-groups, BN); scalar weights.
// ---------------------------------------------------------------------------
__global__ __launch_bounds__(256) void k_xdbl(const float* __restrict__ xc,
                                              const float* __restrict__ xpw,
                                              float* __restrict__ xdp) {
    const int part = blockIdx.y & 3, jg = blockIdx.y >> 2, b = blockIdx.z;
    const int l = blockIdx.x * 256 + threadIdx.x;
    const int d0 = part * 96;
    const int j0 = jg * 22;
    float acc[22];
#pragma unroll
    for (int j = 0; j < 22; ++j) acc[j] = 0.f;
    const float* xcb = xc + ((size_t)b * DI + d0) * LSEQ + l;
    const float* wb  = xpw + (size_t)j0 * DI + d0;
    for (int dd = 0; dd < 96; dd += 4) {
        float v0 = xcb[(size_t)dd * LSEQ];
        float v1 = xcb[(size_t)(dd + 1) * LSEQ];
        float v2 = xcb[(size_t)(dd + 2) * LSEQ];
        float v3 = xcb[(size_t)(dd + 3) * LSEQ];
#pragma unroll
        for (int j = 0; j < 22; ++j) {
            const float* wj = wb + (size_t)j * DI + dd;   // uniform -> SGPR
            acc[j] = fmaf(wj[0], v0, fmaf(wj[1], v1, fmaf(wj[2], v2, fmaf(wj[3], v3, acc[j]))));
        }
    }
    float* dst = xdp + (size_t)(part * BN + b) * NJ * LSEQ + (size_t)j0 * LSEQ + l;
#pragma unroll
    for (int j = 0; j < 22; ++j) dst[(size_t)j * LSEQ] = acc[j];
}

// ---------------------------------------------------------------------------
// K3c: reduce partials; route rows to dtr / B_t / C_t  ((b,n,L) layouts).
// ---------------------------------------------------------------------------
__global__ __launch_bounds__(256) void k_xdbl_reduce(const float* __restrict__ xdp,
                                                     float* __restrict__ dtr,
                                                     float* __restrict__ Bm,
                                                     float* __restrict__ Cm) {
    const int j = blockIdx.y, b = blockIdx.z;
    const int l = blockIdx.x * 256 + threadIdx.x;
    float s = 0.f;
#pragma unroll
    for (int p = 0; p < 4; ++p)
        s += xdp[(size_t)(p * BN + b) * NJ * LSEQ + (size_t)j * LSEQ + l];
    if (j < DTRK)            dtr[((size_t)b * DTRK + j) * LSEQ + l] = s;
    else if (j < DTRK + DS)  Bm[((size_t)b * DS + (j - DTRK)) * LSEQ + l] = s;
    else                     Cm[((size_t)b * DS + (j - DTRK - DS)) * LSEQ + l] = s;
}

// ---------------------------------------------------------------------------
// K3b: dt = softplus(dt_r @ dtw^T + dtb); scalar weights, no LDS.
// ---------------------------------------------------------------------------
__global__ __launch_bounds__(256) void k_dt(const float* __restrict__ dtr,
                                            const float* __restrict__ dtw,
                                            const float* __restrict__ dtb,
                                            float* __restrict__ dt) {
    const int e0 = blockIdx.y * 16, b = blockIdx.z;
    const int l = blockIdx.x * 256 + threadIdx.x;
    float acc[16];
#pragma unroll
    for (int e = 0; e < 16; ++e) acc[e] = 0.f;
    const float* rb = dtr + (size_t)b * DTRK * LSEQ + l;
#pragma unroll
    for (int r = 0; r < DTRK; ++r) {
        float v = rb[(size_t)r * LSEQ];
#pragma unroll
        for (int e = 0; e < 16; ++e)
            acc[e] = fmaf(dtw[(size_t)(e0 + e) * DTRK + r], v, acc[e]);   // uniform
    }
    float* dst = dt + ((size_t)b * DI + e0) * LSEQ + l;
#pragma unroll
    for (int e = 0; e < 16; ++e) dst[(size_t)e * LSEQ] = softplus_f(acc[e] + dtb[e0 + e]);
}

// ---------------------------------------------------------------------------
// K4a: scan pass 1 — per-segment (P,H) aggregates, n-outer, shuffle scan.
// ---------------------------------------------------------------------------
__global__ __launch_bounds__(256) void k_scan1(const float* __restrict__ dt,
                                               const float* __restrict__ xc,
                                               const float* __restrict__ Bm,
                                               const float* __restrict__ A_log,
                                               float* __restrict__ ws2) {
    const int lane = threadIdx.x & 63;
    const int s = blockIdx.x * 4 + (threadIdx.x >> 6);
    const int d = blockIdx.y, b = blockIdx.z;
    const int bd = b * DI + d;
    const size_t rowoff = ((size_t)b * DI + d) * LSEQ + s * SEG;
    const int l0 = lane * CHK;
    float4 da = *(const float4*)(dt + rowoff + l0);
    float4 db = *(const float4*)(dt + rowoff + l0 + 4);
    float4 xa = *(const float4*)(xc + rowoff + l0);
    float4 xb = *(const float4*)(xc + rowoff + l0 + 4);
    float dt8[8] = {da.x, da.y, da.z, da.w, db.x, db.y, db.z, db.w};
    float dx8[8] = {da.x * xa.x, da.y * xa.y, da.z * xa.z, da.w * xa.w,
                    db.x * xb.x, db.y * xb.y, db.z * xb.z, db.w * xb.w};
    const float* Alogd = A_log + (size_t)d * DS;
    float* wout = ws2 + (size_t)(bd * NSPLIT + s) * 32;

    for (int n = 0; n < DS; ++n) {
        const float An = -__expf(Alogd[n]);
        const float* Bn = Bm + ((size_t)(b * DS + n)) * LSEQ + s * SEG + l0;
        float4 Ba = *(const float4*)Bn;
        float4 Bb = *(const float4*)(Bn + 4);
        float B8[8] = {Ba.x, Ba.y, Ba.z, Ba.w, Bb.x, Bb.y, Bb.z, Bb.w};
        float p = 1.f, h = 0.f;
#pragma unroll
        for (int i = 0; i < CHK; ++i) {
            float dA = __expf(dt8[i] * An);
            h = fmaf(dA, h, dx8[i] * B8[i]);
            p *= dA;
        }
        wave_scan_ph(p, h, lane);
        if (lane == 63) { wout[n] = p; wout[16 + n] = h; }
    }
}

// ---------------------------------------------------------------------------
// K4b: scan the 8 segment aggregates per (b,d,n) → exclusive carry-in ws3.
// ---------------------------------------------------------------------------
__global__ __launch_bounds__(256) void k_scan2(const float* __restrict__ ws2,
                                               float* __restrict__ ws3) {
    const int t = blockIdx.x * 256 + threadIdx.x;   // (bd)*16 + n
    const int n = t & 15;
    const int bd = t >> 4;
    float hc = 0.f;
#pragma unroll
    for (int s = 0; s < NSPLIT; ++s) {
        const float* w = ws2 + (size_t)(bd * NSPLIT + s) * 32;
        float P = w[n], H = w[16 + n];
        ws3[(size_t)(bd * NSPLIT + s) * DS + n] = hc;
        hc = fmaf(P, hc, H);
    }
}

// ---------------------------------------------------------------------------
// K4c: scan pass 3 — n-outer, shuffle scan, replay accumulating y, gate.
// ---------------------------------------------------------------------------
__global__ __launch_bounds__(256) void k_scan3(const float* __restrict__ dt,
                                               const float* __restrict__ xc,
                                               const float* __restrict__ Bm,
                                               const float* __restrict__ Cm,
                                               const float* __restrict__ zs,
                                               const float* __restrict__ A_log,
                                               const float* __restrict__ Dp,
                                               const float* __restrict__ ws3,
                                               float* __restrict__ g) {
    const int lane = threadIdx.x & 63;
    const int s = blockIdx.x * 4 + (threadIdx.x >> 6);
    const int d = blockIdx.y, b = blockIdx.z;
    const int bd = b * DI + d;
    const size_t rowoff = ((size_t)b * DI + d) * LSEQ + s * SEG;
    const int l0 = lane * CHK;
    float4 da = *(const float4*)(dt + rowoff + l0);
    float4 db = *(const float4*)(dt + rowoff + l0 + 4);
    float4 xa = *(const float4*)(xc + rowoff + l0);
    float4 xb = *(const float4*)(xc + rowoff + l0 + 4);
    float4 za = *(const float4*)(zs + rowoff + l0);
    float4 zb = *(const float4*)(zs + rowoff + l0 + 4);
    float dt8[8] = {da.x, da.y, da.z, da.w, db.x, db.y, db.z, db.w};
    float xc8[8] = {xa.x, xa.y, xa.z, xa.w, xb.x, xb.y, xb.z, xb.w};
    float z8[8]  = {za.x, za.y, za.z, za.w, zb.x, zb.y, zb.z, zb.w};
    float dx8[8];
#pragma unroll
    for (int i = 0; i < CHK; ++i) dx8[i] = dt8[i] * xc8[i];
    float y8[8] = {0.f, 0.f, 0.f, 0.f, 0.f, 0.f, 0.f, 0.f};
    const float* Alogd = A_log + (size_t)d * DS;
    const float* carry = ws3 + (size_t)(bd * NSPLIT + s) * DS;

    for (int n = 0; n < DS; ++n) {
        const float An = -__expf(Alogd[n]);
        const size_t nloff = ((size_t)(b * DS + n)) * LSEQ + s * SEG + l0;
        float4 Ba = *(const float4*)(Bm + nloff);
        float4 Bb = *(const float4*)(Bm + nloff + 4);
        float4 Ca = *(const float4*)(Cm + nloff);
        float4 Cb = *(const float4*)(Cm + nloff + 4);
        float B8[8] = {Ba.x, Ba.y, Ba.z, Ba.w, Bb.x, Bb.y, Bb.z, Bb.w};
        float C8[8] = {Ca.x, Ca.y, Ca.z, Ca.w, Cb.x, Cb.y, Cb.z, Cb.w};
        float dA8[8];
        float p = 1.f, h = 0.f;
#pragma unroll
        for (int i = 0; i < CHK; ++i) {
            float dA = __expf(dt8[i] * An);
            dA8[i] = dA;
            h = fmaf(dA, h, dx8[i] * B8[i]);
            p *= dA;
        }
        wave_scan_ph(p, h, lane);
        float Pe = __shfl_up(p, 1u);
        float He = __shfl_up(h, 1u);
        if (lane == 0) { Pe = 1.f; He = 0.f; }
        float hv = fmaf(Pe, carry[n], He);   // h entering this lane's chunk
#pragma unroll
        for (int i = 0; i < CHK; ++i) {
            hv = fmaf(dA8[i], hv, dx8[i] * B8[i]);
            y8[i] = fmaf(hv, C8[i], y8[i]);
        }
    }
    const float Dd = Dp[d];
    float out8[8];
#pragma unroll
    for (int i = 0; i < CHK; ++i) out8[i] = fmaf(Dd, xc8[i], y8[i]) * z8[i];
    float* grow = g + rowoff;
    *(float4*)(grow + l0)     = make_float4(out8[0], out8[1], out8[2], out8[3]);
    *(float4*)(grow + l0 + 4) = make_float4(out8[4], out8[5], out8[6], out8[7]);
}

// ---------------------------------------------------------------------------
// K5: out_proj.  grid (8, 24, BN), 2 l/thread, 8 c per block; scalar weights.
// ---------------------------------------------------------------------------
__global__ __launch_bounds__(256) void k_outproj(const float* __restrict__ g,
                                                 const float* __restrict__ wout,
                                                 float* __restrict__ out) {
    const int c0 = blockIdx.y * 8, b = blockIdx.z;
    const int l0 = blockIdx.x * 512 + threadIdx.x * 2;
    float2 acc[8];
#pragma unroll
    for (int cc = 0; cc < 8; ++cc) acc[cc] = make_float2(0.f, 0.f);
    const float* gb = g + (size_t)b * DI * LSEQ + l0;
    const float* wb = wout + (size_t)c0 * DI;
    for (int d = 0; d < DI; d += 4) {
        float2 g0 = *(const float2*)(gb + (size_t)d * LSEQ);
        float2 g1 = *(const float2*)(gb + (size_t)(d + 1) * LSEQ);
        float2 g2 = *(const float2*)(gb + (size_t)(d + 2) * LSEQ);
        float2 g3 = *(const float2*)(gb + (size_t)(d + 3) * LSEQ);
#pragma unroll
        for (int cc = 0; cc < 8; ++cc) {
            const float* wc = wb + (size_t)cc * DI + d;   // uniform -> SGPR
            float w0 = wc[0], w1 = wc[1], w2 = wc[2], w3 = wc[3];
            acc[cc].x = fmaf(w0, g0.x, fmaf(w1, g1.x, fmaf(w2, g2.x, fmaf(w3, g3.x, acc[cc].x))));
            acc[cc].y = fmaf(w0, g0.y, fmaf(w1, g1.y, fmaf(w2, g2.y, fmaf(w3, g3.y, acc[cc].y))));
        }
    }
#pragma unroll
    for (int cc = 0; cc < 8; ++cc)
        *(float2*)(out + ((size_t)b * CD + c0 + cc) * LSEQ + l0) = acc[cc];
}

extern "C" void kernel_launch(void* const* d_in, const int* in_sizes, int n_in,
                              void* d_out, int out_size, void* d_ws, size_t ws_size,
                              hipStream_t stream) {
    const float* x     = (const float*)d_in[0];
    const float* w_in  = (const float*)d_in[1];
    const float* cw    = (const float*)d_in[2];
    const float* cb    = (const float*)d_in[3];
    const float* xpw   = (const float*)d_in[4];
    const float* dtw   = (const float*)d_in[5];
    const float* dtbv  = (const float*)d_in[6];
    const float* A_log = (const float*)d_in[7];
    const float* Dp    = (const float*)d_in[8];
    const float* wout  = (const float*)d_in[9];
    float* out = (float*)d_out;

    float* ws = (float*)d_ws;
    const size_t NBL = (size_t)BN * DI * LSEQ;            // 6,291,456 floats
    float* xp  = ws;                                      // (b,384,L)
    float* zs  = xp + NBL;                                // silu(z)
    float* xc  = zs + NBL;                                // conv out
    float* dt  = xc + NBL;                                // softplus dt
    float* Bm  = dt + NBL;                                // (b,16,L) transposed
    float* Cm  = Bm + (size_t)BN * LSEQ * DS;             // (b,16,L) transposed
    float* dtr = Cm + (size_t)BN * LSEQ * DS;             // (b,12,L)
    float* xdp = dtr + (size_t)BN * DTRK * LSEQ;          // 4 x (b,44,L); dead after k_dt
    float* g   = xp;                                      // reuse xp after conv
    float* ws2 = xdp;                                     // 12288 * 32 floats
    float* ws3 = ws2 + (size_t)BN * DI * NSPLIT * 32;     // 12288 * 16 floats

    k_inproj     <<<dim3(4, 96, BN), 256, 0, stream>>>(x, w_in, xp, zs);
    k_conv       <<<dim3(4, DI, BN), 256, 0, stream>>>(xp, cw, cb, xc);
    k_xdbl       <<<dim3(16, 8, BN), 256, 0, stream>>>(xc, xpw, xdp);
    k_xdbl_reduce<<<dim3(16, NJ, BN), 256, 0, stream>>>(xdp, dtr, Bm, Cm);
    k_dt         <<<dim3(16, 24, BN), 256, 0, stream>>>(dtr, dtw, dtbv, dt);
    k_scan1      <<<dim3(NSPLIT / 4, DI, BN), 256, 0, stream>>>(dt, xc, Bm, A_log, ws2);
    k_scan2      <<<dim3(96), 256, 0, stream>>>(ws2, ws3);
    k_scan3      <<<dim3(NSPLIT / 4, DI, BN), 256, 0, stream>>>(dt, xc, Bm, Cm, zs, A_log, Dp, ws3, g);
    k_outproj    <<<dim3(8, 24, BN), 256, 0, stream>>>(g, wout, out);
}